// Round 5
// baseline (869.488 us; speedup 1.0000x reference)
//
#include <hip/hip_runtime.h>
#include <math.h>

#define DIMX   1024
#define NHEADS 16
#define HD     64
#define BATCH  4
#define SEQ    2048
#define NM     (BATCH * NHEADS * SEQ * HD)   // 8388608 elems per Q/K/V tensor

typedef unsigned short ushort_t;
typedef __attribute__((ext_vector_type(8))) short bf16x8;
typedef __attribute__((ext_vector_type(4))) float f32x4;

#define MFMA16(a, b, c) __builtin_amdgcn_mfma_f32_16x16x32_bf16(a, b, c, 0, 0, 0)

// round-to-nearest-even fp32 -> bf16 bits
__device__ __forceinline__ ushort_t f2bf(float x) {
    unsigned u = __float_as_uint(x);
    u += 0x7fffu + ((u >> 16) & 1u);
    return (ushort_t)(u >> 16);
}
__device__ __forceinline__ float bf2f(ushort_t h) {
    return __uint_as_float(((unsigned)h) << 16);
}

// async global->LDS, 16B per lane; LDS base wave-uniform (HW adds lane*16)
#define GLOAD_LDS16(g, l) \
    __builtin_amdgcn_global_load_lds((const __attribute__((address_space(1))) unsigned int*)(g), \
                                     (__attribute__((address_space(3))) unsigned int*)(l), 16, 0, 0)

// DPP 16-lane butterfly reductions (VALU pipe, not DS):
// quad_perm(1,0,3,2)=0xB1 (xor1), quad_perm(2,3,0,1)=0x4E (xor2),
// row_half_mirror=0x141 (xor4 once 4-groups uniform), row_mirror=0x140 (xor8).
template<int CTRL>
__device__ __forceinline__ float dpp_mov(float x) {
    return __int_as_float(__builtin_amdgcn_update_dpp(0, __float_as_int(x), CTRL, 0xF, 0xF, true));
}
__device__ __forceinline__ float row_max16(float x) {
    x = fmaxf(x, dpp_mov<0xB1>(x));
    x = fmaxf(x, dpp_mov<0x4E>(x));
    x = fmaxf(x, dpp_mov<0x141>(x));
    x = fmaxf(x, dpp_mov<0x140>(x));
    return x;
}
__device__ __forceinline__ float row_sum16(float x) {
    x += dpp_mov<0xB1>(x);
    x += dpp_mov<0x4E>(x);
    x += dpp_mov<0x141>(x);
    x += dpp_mov<0x140>(x);
    return x;
}

// ---------------------------------------------------------------------------
// convert_x: split x fp32 -> Xhi, Xlo bf16.  (unchanged from r4)
// ---------------------------------------------------------------------------
__global__ __launch_bounds__(256) void convert_x(
    const float* __restrict__ x, ushort_t* __restrict__ Xh, ushort_t* __restrict__ Xl)
{
    int i = blockIdx.x * 256 + threadIdx.x;
    #pragma unroll
    for (int t = 0; t < 4; t++) {
        int idx = t * 524288 + i;
        f32x4 v = ((const f32x4*)x)[idx];
        ushort4 hi, lo;
        hi.x = f2bf(v[0]); lo.x = f2bf(v[0] - bf2f(hi.x));
        hi.y = f2bf(v[1]); lo.y = f2bf(v[1] - bf2f(hi.y));
        hi.z = f2bf(v[2]); lo.z = f2bf(v[2] - bf2f(hi.z));
        hi.w = f2bf(v[3]); lo.w = f2bf(v[3] - bf2f(hi.w));
        ((ushort4*)Xh)[idx] = hi;
        ((ushort4*)Xl)[idx] = lo;
    }
}

// ---------------------------------------------------------------------------
// convert_w: transpose w[n][d][e] -> Wt[e'][d], split hi/lo bf16. (unchanged)
// ---------------------------------------------------------------------------
__global__ __launch_bounds__(256) void convert_w(
    const float* __restrict__ wk, const float* __restrict__ wq, const float* __restrict__ wv,
    ushort_t* __restrict__ Bqh, ushort_t* __restrict__ Bql, ushort_t* __restrict__ Bvh)
{
    __shared__ float Ts[64][65];
    const int bid = blockIdx.x;
    const int mat = bid >> 8;
    const int rem = bid & 255;
    const int n  = rem >> 4;
    const int dt = rem & 15;
    const float* w = (mat == 0) ? wq : (mat == 1) ? wk : wv;
    const int tid = threadIdx.x;

    #pragma unroll
    for (int t = 0; t < 16; t++) {
        int i = tid + t * 256;
        int r = i >> 6, e = i & 63;
        Ts[r][e] = w[((size_t)n * 1024 + dt * 64 + r) * 64 + e];
    }
    __syncthreads();
    #pragma unroll
    for (int t = 0; t < 16; t++) {
        int i = tid + t * 256;
        int e = i >> 6, r = i & 63;
        float v = Ts[r][e];
        ushort_t hi = f2bf(v);
        size_t o = (size_t)(n * 64 + e) * 1024 + dt * 64 + r;
        if (mat < 2) {
            Bqh[(size_t)mat * 1048576 + o] = hi;
            Bql[(size_t)mat * 1048576 + o] = f2bf(v - bf2f(hi));
        } else {
            Bvh[o] = hi;
        }
    }
}

// ---------------------------------------------------------------------------
// proj_qk: 3-pass split-bf16 MFMA GEMM. (unchanged from r4)
// ---------------------------------------------------------------------------
__global__ __launch_bounds__(256) void proj_qk(
    const ushort_t* __restrict__ Xh, const ushort_t* __restrict__ Xl,
    const ushort_t* __restrict__ Bh, const ushort_t* __restrict__ Bl,
    float* __restrict__ Qf, ushort_t* __restrict__ Khi, ushort_t* __restrict__ Klo)
{
    __shared__ __align__(16) ushort_t Ah[128 * 64];
    __shared__ __align__(16) ushort_t Al[128 * 64];
    __shared__ __align__(16) ushort_t Bhs[128 * 64];
    __shared__ __align__(16) ushort_t Bls[128 * 64];

    const int mt = blockIdx.x, nt = blockIdx.y;
    const int tid = threadIdx.x;
    const int w = tid >> 6, lane = tid & 63, col = lane & 15, quad = lane >> 4;
    const int wm = w & 1, wn = w >> 1;

    f32x4 acc[4][4] = {};

    for (int kc = 0; kc < 1024; kc += 64) {
        __syncthreads();
        #pragma unroll
        for (int i = 0; i < 4; i++) {
            int s = (w * 4 + i) * 64 + lane;
            int r = s >> 3, j = s & 7, g = j ^ (r & 7);
            size_t aoff = (size_t)(mt * 128 + r) * 1024 + kc + g * 8;
            size_t boff = (size_t)(nt * 128 + r) * 1024 + kc + g * 8;
            GLOAD_LDS16(Xh + aoff, Ah  + (size_t)(w * 4 + i) * 512);
            GLOAD_LDS16(Xl + aoff, Al  + (size_t)(w * 4 + i) * 512);
            GLOAD_LDS16(Bh + boff, Bhs + (size_t)(w * 4 + i) * 512);
            GLOAD_LDS16(Bl + boff, Bls + (size_t)(w * 4 + i) * 512);
        }
        __syncthreads();
        #pragma unroll
        for (int kk = 0; kk < 2; kk++) {
            bf16x8 a_h[4], a_l[4], b_h[4], b_l[4];
            const int gi = kk * 4 + quad;
            #pragma unroll
            for (int t = 0; t < 4; t++) {
                int rA = wm * 64 + t * 16 + col;
                int jA = gi ^ (rA & 7);
                a_h[t] = *(const bf16x8*)&Ah[(rA * 8 + jA) * 8];
                a_l[t] = *(const bf16x8*)&Al[(rA * 8 + jA) * 8];
                int rB = wn * 64 + t * 16 + col;
                int jB = gi ^ (rB & 7);
                b_h[t] = *(const bf16x8*)&Bhs[(rB * 8 + jB) * 8];
                b_l[t] = *(const bf16x8*)&Bls[(rB * 8 + jB) * 8];
            }
            #pragma unroll
            for (int t = 0; t < 4; t++)
                #pragma unroll
                for (int u = 0; u < 4; u++) {
                    acc[t][u] = MFMA16(a_h[t], b_h[u], acc[t][u]);
                    acc[t][u] = MFMA16(a_l[t], b_h[u], acc[t][u]);
                    acc[t][u] = MFMA16(a_h[t], b_l[u], acc[t][u]);
                }
        }
    }

    const bool isQ = (nt < 8);
    #pragma unroll
    for (int t = 0; t < 4; t++) {
        #pragma unroll
        for (int u = 0; u < 4; u++) {
            int np = nt * 128 + wn * 64 + u * 16 + col;
            int head = (np >> 6) & 15, e = np & 63;
            #pragma unroll
            for (int rr = 0; rr < 4; rr++) {
                int mm = mt * 128 + wm * 64 + t * 16 + quad * 4 + rr;
                int bi = mm >> 11, l = mm & 2047;
                size_t base = (((size_t)bi * NHEADS + head) * SEQ + l) * HD + e;
                float v = acc[t][u][rr];
                if (isQ) {
                    Qf[base] = v;
                } else {
                    ushort_t hi = f2bf(v);
                    Khi[base] = hi;
                    Klo[base] = f2bf(v - bf2f(hi));
                }
            }
        }
    }
}

// ---------------------------------------------------------------------------
// proj_v: 1-pass bf16, operand-swapped for transposed-V output. (unchanged)
// ---------------------------------------------------------------------------
__global__ __launch_bounds__(256) void proj_v(
    const ushort_t* __restrict__ Wvh, const ushort_t* __restrict__ Xh,
    ushort_t* __restrict__ Vt)
{
    __shared__ __align__(16) ushort_t Ah[128 * 64];
    __shared__ __align__(16) ushort_t Bhs[128 * 64];

    const int mt = blockIdx.x, nt = blockIdx.y;
    const int tid = threadIdx.x;
    const int w = tid >> 6, lane = tid & 63, col = lane & 15, quad = lane >> 4;
    const int wm = w & 1, wn = w >> 1;

    f32x4 acc[4][4] = {};

    for (int kc = 0; kc < 1024; kc += 64) {
        __syncthreads();
        #pragma unroll
        for (int i = 0; i < 4; i++) {
            int s = (w * 4 + i) * 64 + lane;
            int r = s >> 3, j = s & 7, g = j ^ (r & 7);
            size_t aoff = (size_t)(mt * 128 + r) * 1024 + kc + g * 8;
            size_t boff = (size_t)(nt * 128 + r) * 1024 + kc + g * 8;
            GLOAD_LDS16(Wvh + aoff, Ah  + (size_t)(w * 4 + i) * 512);
            GLOAD_LDS16(Xh  + boff, Bhs + (size_t)(w * 4 + i) * 512);
        }
        __syncthreads();
        #pragma unroll
        for (int kk = 0; kk < 2; kk++) {
            bf16x8 a_h[4], b_h[4];
            const int gi = kk * 4 + quad;
            #pragma unroll
            for (int t = 0; t < 4; t++) {
                int rA = wm * 64 + t * 16 + col;
                a_h[t] = *(const bf16x8*)&Ah[(rA * 8 + (gi ^ (rA & 7))) * 8];
                int rB = wn * 64 + t * 16 + col;
                b_h[t] = *(const bf16x8*)&Bhs[(rB * 8 + (gi ^ (rB & 7))) * 8];
            }
            #pragma unroll
            for (int t = 0; t < 4; t++)
                #pragma unroll
                for (int u = 0; u < 4; u++)
                    acc[t][u] = MFMA16(a_h[t], b_h[u], acc[t][u]);
        }
    }

    #pragma unroll
    for (int t = 0; t < 4; t++) {
        #pragma unroll
        for (int rr = 0; rr < 4; rr++) {
            int ep = mt * 128 + wm * 64 + t * 16 + quad * 4 + rr;
            int head = ep >> 6, e = ep & 63;
            #pragma unroll
            for (int u = 0; u < 4; u++) {
                int lg = nt * 128 + wn * 64 + u * 16 + col;
                int bi = lg >> 11, l = lg & 2047;
                Vt[(((size_t)bi * NHEADS + head) * HD + e) * SEQ + l] = f2bf(acc[t][u][rr]);
            }
        }
    }
}

// ---------------------------------------------------------------------------
// Flash attention, barrier-free. K/V fragments loaded DIRECTLY from global
// (B-frag 16B granules are contiguous in the [l][e] / [e][l] layouts) —
// no LDS staging, no __syncthreads. LDS holds only the per-wave P round-trip
// (C-layout -> A-layout). Softmax reductions on VALU via DPP (quad_perm +
// row mirrors). Q pre-scaled by 0.125*log2e -> exp2-domain softmax.
// ---------------------------------------------------------------------------
__global__ __launch_bounds__(256) void attn_mfma_kernel(
    const float* __restrict__ Qf, const ushort_t* __restrict__ Khi,
    const ushort_t* __restrict__ Klo, const ushort_t* __restrict__ Vt,
    float* __restrict__ out)
{
    __shared__ __align__(16) ushort_t Ps[4 * 16 * 80];   // per-wave P tile, pad 80 (16B-aligned rows)

    const int qt  = blockIdx.x;       // 0..31
    const int bn  = blockIdx.y;       // 0..63
    const int tid = threadIdx.x;
    const int w    = tid >> 6;
    const int lane = tid & 63;
    const int col  = lane & 15;
    const int quad = lane >> 4;

    const ushort_t* Kh_g = Khi + (size_t)bn * SEQ * HD;
    const ushort_t* Kl_g = Klo + (size_t)bn * SEQ * HD;
    const ushort_t* Vt_g = Vt  + (size_t)bn * HD * SEQ;

    // ---- Q A-fragments in registers, scaled by log2e/sqrt(HD), split hi/lo
    union { bf16x8 v; short s[8]; } qh[2], ql[2];
    {
        const int qrow = qt * 64 + w * 16 + col;
        const float* qp = Qf + ((size_t)bn * SEQ + qrow) * HD;
        #pragma unroll
        for (int ks = 0; ks < 2; ks++) {
            float qv[8];
            f32x4 a = *(const f32x4*)(qp + ks * 32 + quad * 8);
            f32x4 b = *(const f32x4*)(qp + ks * 32 + quad * 8 + 4);
            qv[0]=a[0]; qv[1]=a[1]; qv[2]=a[2]; qv[3]=a[3];
            qv[4]=b[0]; qv[5]=b[1]; qv[6]=b[2]; qv[7]=b[3];
            #pragma unroll
            for (int j = 0; j < 8; j++) {
                float xsc = qv[j] * (0.125f * 1.44269504088896f);
                ushort_t hi = f2bf(xsc);
                ushort_t lo = f2bf(xsc - bf2f(hi));
                qh[ks].s[j] = (short)hi;
                ql[ks].s[j] = (short)lo;
            }
        }
    }

    f32x4 O[4] = {{0,0,0,0},{0,0,0,0},{0,0,0,0},{0,0,0,0}};
    float m_i[4] = {-1e30f, -1e30f, -1e30f, -1e30f};
    float l_i[4] = {0.f, 0.f, 0.f, 0.f};
    ushort_t* Pw = &Ps[w * 16 * 80];

    for (int ch = 0; ch < 32; ch++) {
        // ---- S = Q K^T: K B-frags straight from global ([l][e]: key-row, 16B contig)
        f32x4 S[4] = {{0,0,0,0},{0,0,0,0},{0,0,0,0},{0,0,0,0}};
        #pragma unroll
        for (int ks = 0; ks < 2; ks++) {
            #pragma unroll
            for (int t = 0; t < 4; t++) {
                size_t koff = (size_t)(ch * 64 + t * 16 + col) * HD + ks * 32 + quad * 8;
                bf16x8 kh = *(const bf16x8*)&Kh_g[koff];
                bf16x8 kl = *(const bf16x8*)&Kl_g[koff];
                S[t] = MFMA16(qh[ks].v, kh, S[t]);
                S[t] = MFMA16(ql[ks].v, kh, S[t]);
                S[t] = MFMA16(qh[ks].v, kl, S[t]);
            }
        }

        // ---- online softmax in exp2 domain; DPP reductions (VALU pipe)
        float mnew[4], al[4], ps[4];
        #pragma unroll
        for (int r = 0; r < 4; r++) {
            float mx = fmaxf(fmaxf(S[0][r], S[1][r]), fmaxf(S[2][r], S[3][r]));
            mx = row_max16(mx);
            mnew[r] = fmaxf(m_i[r], mx);
            al[r]   = exp2f(m_i[r] - mnew[r]);
            m_i[r]  = mnew[r];
            ps[r]   = 0.f;
        }
        #pragma unroll
        for (int t = 0; t < 4; t++) {
            #pragma unroll
            for (int r = 0; r < 4; r++) {
                float p = exp2f(S[t][r] - mnew[r]);
                ps[r] += p;
                Pw[(quad * 4 + r) * 80 + t * 16 + col] = f2bf(p);
            }
        }
        #pragma unroll
        for (int r = 0; r < 4; r++) {
            l_i[r] = l_i[r] * al[r] + row_sum16(ps[r]);
            O[0][r] *= al[r]; O[1][r] *= al[r]; O[2][r] *= al[r]; O[3][r] *= al[r];
        }

        // ---- O += P V: P A-frag via per-wave LDS round-trip; V B-frags from
        // global ([e][l]: e-row, 16B contig along keys)
        #pragma unroll
        for (int ks = 0; ks < 2; ks++) {
            bf16x8 pf = *(const bf16x8*)&Pw[col * 80 + ks * 32 + quad * 8];
            #pragma unroll
            for (int t = 0; t < 4; t++) {
                size_t voff = (size_t)(t * 16 + col) * SEQ + ch * 64 + ks * 32 + quad * 8;
                bf16x8 vf = *(const bf16x8*)&Vt_g[voff];
                O[t] = MFMA16(pf, vf, O[t]);
            }
        }
    }

    // ---- epilogue: out[b][l][n*64+e] = O / l
    const int b = bn >> 4, n = bn & 15;
    #pragma unroll
    for (int t = 0; t < 4; t++) {
        #pragma unroll
        for (int r = 0; r < 4; r++) {
            int l = qt * 64 + w * 16 + quad * 4 + r;
            out[((size_t)(b * SEQ + l)) * (NHEADS * HD) + n * HD + t * 16 + col] = O[t][r] / l_i[r];
        }
    }
}

// ---------------------------------------------------------------------------
extern "C" void kernel_launch(void* const* d_in, const int* in_sizes, int n_in,
                              void* d_out, int out_size, void* d_ws, size_t ws_size,
                              hipStream_t stream) {
    const float* x  = (const float*)d_in[0];
    const float* wk = (const float*)d_in[1];
    const float* wq = (const float*)d_in[2];
    const float* wv = (const float*)d_in[3];
    float* out = (float*)d_out;

    // ws layout (111 MB): Xh | Xl (aliased by Vt after proj_qk) | Bqh | Bql | Bvh | Qf | Khi | Klo
    ushort_t* Xh  = (ushort_t*)d_ws;
    ushort_t* Xl  = Xh + NM;
    ushort_t* Vt  = Xl;                      // alias: Xl dead once proj_qk finishes
    ushort_t* Bqh = Xl + NM;                 // [2048][1024]
    ushort_t* Bql = Bqh + 2097152;
    ushort_t* Bvh = Bql + 2097152;           // [1024][1024]
    float*    Qf  = (float*)(Bvh + 1048576);
    ushort_t* Khi = (ushort_t*)(Qf + NM);
    ushort_t* Klo = Khi + NM;

    convert_x<<<2048, 256, 0, stream>>>(x, Xh, Xl);
    convert_w<<<768, 256, 0, stream>>>(wk, wq, wv, Bqh, Bql, Bvh);
    proj_qk<<<dim3(64, 16), 256, 0, stream>>>(Xh, Xl, Bqh, Bql, Qf, Khi, Klo);
    proj_v<<<dim3(8, 64), 256, 0, stream>>>(Bvh, Xh, Vt);
    attn_mfma_kernel<<<dim3(32, 64), 256, 0, stream>>>(Qf, Khi, Klo, Vt, out);
}

// Round 6
// 438.587 us; speedup vs baseline: 1.9825x; 1.9825x over previous
//
#include <hip/hip_runtime.h>
#include <math.h>

#define DIMX   1024
#define NHEADS 16
#define HD     64
#define BATCH  4
#define SEQ    2048
#define NM     (BATCH * NHEADS * SEQ * HD)   // 8388608 elems per Q/K/V tensor

typedef unsigned short ushort_t;
typedef __attribute__((ext_vector_type(8))) short bf16x8;
typedef __attribute__((ext_vector_type(4))) float f32x4;

#define MFMA16(a, b, c) __builtin_amdgcn_mfma_f32_16x16x32_bf16(a, b, c, 0, 0, 0)

// round-to-nearest-even fp32 -> bf16 bits
__device__ __forceinline__ ushort_t f2bf(float x) {
    unsigned u = __float_as_uint(x);
    u += 0x7fffu + ((u >> 16) & 1u);
    return (ushort_t)(u >> 16);
}
__device__ __forceinline__ float bf2f(ushort_t h) {
    return __uint_as_float(((unsigned)h) << 16);
}

// async global->LDS, 16B per lane; LDS base wave-uniform (HW adds lane*16)
#define GLOAD_LDS16(g, l) \
    __builtin_amdgcn_global_load_lds((const __attribute__((address_space(1))) unsigned int*)(g), \
                                     (__attribute__((address_space(3))) unsigned int*)(l), 16, 0, 0)

// DPP 16-lane butterfly reductions (VALU pipe, not DS) — verified r5.
template<int CTRL>
__device__ __forceinline__ float dpp_mov(float x) {
    return __int_as_float(__builtin_amdgcn_update_dpp(0, __float_as_int(x), CTRL, 0xF, 0xF, true));
}
__device__ __forceinline__ float row_max16(float x) {
    x = fmaxf(x, dpp_mov<0xB1>(x));
    x = fmaxf(x, dpp_mov<0x4E>(x));
    x = fmaxf(x, dpp_mov<0x141>(x));
    x = fmaxf(x, dpp_mov<0x140>(x));
    return x;
}
__device__ __forceinline__ float row_sum16(float x) {
    x += dpp_mov<0xB1>(x);
    x += dpp_mov<0x4E>(x);
    x += dpp_mov<0x141>(x);
    x += dpp_mov<0x140>(x);
    return x;
}

// ---------------------------------------------------------------------------
// convert_x: split x fp32 -> Xhi, Xlo bf16.  (unchanged)
// ---------------------------------------------------------------------------
__global__ __launch_bounds__(256) void convert_x(
    const float* __restrict__ x, ushort_t* __restrict__ Xh, ushort_t* __restrict__ Xl)
{
    int i = blockIdx.x * 256 + threadIdx.x;
    #pragma unroll
    for (int t = 0; t < 4; t++) {
        int idx = t * 524288 + i;
        f32x4 v = ((const f32x4*)x)[idx];
        ushort4 hi, lo;
        hi.x = f2bf(v[0]); lo.x = f2bf(v[0] - bf2f(hi.x));
        hi.y = f2bf(v[1]); lo.y = f2bf(v[1] - bf2f(hi.y));
        hi.z = f2bf(v[2]); lo.z = f2bf(v[2] - bf2f(hi.z));
        hi.w = f2bf(v[3]); lo.w = f2bf(v[3] - bf2f(hi.w));
        ((ushort4*)Xh)[idx] = hi;
        ((ushort4*)Xl)[idx] = lo;
    }
}

// ---------------------------------------------------------------------------
// convert_w: transpose w[n][d][e] -> Wt[e'][d], split hi/lo bf16. (unchanged)
// ---------------------------------------------------------------------------
__global__ __launch_bounds__(256) void convert_w(
    const float* __restrict__ wk, const float* __restrict__ wq, const float* __restrict__ wv,
    ushort_t* __restrict__ Bqh, ushort_t* __restrict__ Bql, ushort_t* __restrict__ Bvh)
{
    __shared__ float Ts[64][65];
    const int bid = blockIdx.x;
    const int mat = bid >> 8;
    const int rem = bid & 255;
    const int n  = rem >> 4;
    const int dt = rem & 15;
    const float* w = (mat == 0) ? wq : (mat == 1) ? wk : wv;
    const int tid = threadIdx.x;

    #pragma unroll
    for (int t = 0; t < 16; t++) {
        int i = tid + t * 256;
        int r = i >> 6, e = i & 63;
        Ts[r][e] = w[((size_t)n * 1024 + dt * 64 + r) * 64 + e];
    }
    __syncthreads();
    #pragma unroll
    for (int t = 0; t < 16; t++) {
        int i = tid + t * 256;
        int e = i >> 6, r = i & 63;
        float v = Ts[r][e];
        ushort_t hi = f2bf(v);
        size_t o = (size_t)(n * 64 + e) * 1024 + dt * 64 + r;
        if (mat < 2) {
            Bqh[(size_t)mat * 1048576 + o] = hi;
            Bql[(size_t)mat * 1048576 + o] = f2bf(v - bf2f(hi));
        } else {
            Bvh[o] = hi;
        }
    }
}

// ---------------------------------------------------------------------------
// proj_qk: 3-pass split-bf16 MFMA GEMM. (unchanged)
// ---------------------------------------------------------------------------
__global__ __launch_bounds__(256) void proj_qk(
    const ushort_t* __restrict__ Xh, const ushort_t* __restrict__ Xl,
    const ushort_t* __restrict__ Bh, const ushort_t* __restrict__ Bl,
    float* __restrict__ Qf, ushort_t* __restrict__ Khi, ushort_t* __restrict__ Klo)
{
    __shared__ __align__(16) ushort_t Ah[128 * 64];
    __shared__ __align__(16) ushort_t Al[128 * 64];
    __shared__ __align__(16) ushort_t Bhs[128 * 64];
    __shared__ __align__(16) ushort_t Bls[128 * 64];

    const int mt = blockIdx.x, nt = blockIdx.y;
    const int tid = threadIdx.x;
    const int w = tid >> 6, lane = tid & 63, col = lane & 15, quad = lane >> 4;
    const int wm = w & 1, wn = w >> 1;

    f32x4 acc[4][4] = {};

    for (int kc = 0; kc < 1024; kc += 64) {
        __syncthreads();
        #pragma unroll
        for (int i = 0; i < 4; i++) {
            int s = (w * 4 + i) * 64 + lane;
            int r = s >> 3, j = s & 7, g = j ^ (r & 7);
            size_t aoff = (size_t)(mt * 128 + r) * 1024 + kc + g * 8;
            size_t boff = (size_t)(nt * 128 + r) * 1024 + kc + g * 8;
            GLOAD_LDS16(Xh + aoff, Ah  + (size_t)(w * 4 + i) * 512);
            GLOAD_LDS16(Xl + aoff, Al  + (size_t)(w * 4 + i) * 512);
            GLOAD_LDS16(Bh + boff, Bhs + (size_t)(w * 4 + i) * 512);
            GLOAD_LDS16(Bl + boff, Bls + (size_t)(w * 4 + i) * 512);
        }
        __syncthreads();
        #pragma unroll
        for (int kk = 0; kk < 2; kk++) {
            bf16x8 a_h[4], a_l[4], b_h[4], b_l[4];
            const int gi = kk * 4 + quad;
            #pragma unroll
            for (int t = 0; t < 4; t++) {
                int rA = wm * 64 + t * 16 + col;
                int jA = gi ^ (rA & 7);
                a_h[t] = *(const bf16x8*)&Ah[(rA * 8 + jA) * 8];
                a_l[t] = *(const bf16x8*)&Al[(rA * 8 + jA) * 8];
                int rB = wn * 64 + t * 16 + col;
                int jB = gi ^ (rB & 7);
                b_h[t] = *(const bf16x8*)&Bhs[(rB * 8 + jB) * 8];
                b_l[t] = *(const bf16x8*)&Bls[(rB * 8 + jB) * 8];
            }
            #pragma unroll
            for (int t = 0; t < 4; t++)
                #pragma unroll
                for (int u = 0; u < 4; u++) {
                    acc[t][u] = MFMA16(a_h[t], b_h[u], acc[t][u]);
                    acc[t][u] = MFMA16(a_l[t], b_h[u], acc[t][u]);
                    acc[t][u] = MFMA16(a_h[t], b_l[u], acc[t][u]);
                }
        }
    }

    const bool isQ = (nt < 8);
    #pragma unroll
    for (int t = 0; t < 4; t++) {
        #pragma unroll
        for (int u = 0; u < 4; u++) {
            int np = nt * 128 + wn * 64 + u * 16 + col;
            int head = (np >> 6) & 15, e = np & 63;
            #pragma unroll
            for (int rr = 0; rr < 4; rr++) {
                int mm = mt * 128 + wm * 64 + t * 16 + quad * 4 + rr;
                int bi = mm >> 11, l = mm & 2047;
                size_t base = (((size_t)bi * NHEADS + head) * SEQ + l) * HD + e;
                float v = acc[t][u][rr];
                if (isQ) {
                    Qf[base] = v;
                } else {
                    ushort_t hi = f2bf(v);
                    Khi[base] = hi;
                    Klo[base] = f2bf(v - bf2f(hi));
                }
            }
        }
    }
}

// ---------------------------------------------------------------------------
// proj_v: 1-pass bf16, operand-swapped for transposed-V output. (unchanged)
// ---------------------------------------------------------------------------
__global__ __launch_bounds__(256) void proj_v(
    const ushort_t* __restrict__ Wvh, const ushort_t* __restrict__ Xh,
    ushort_t* __restrict__ Vt)
{
    __shared__ __align__(16) ushort_t Ah[128 * 64];
    __shared__ __align__(16) ushort_t Bhs[128 * 64];

    const int mt = blockIdx.x, nt = blockIdx.y;
    const int tid = threadIdx.x;
    const int w = tid >> 6, lane = tid & 63, col = lane & 15, quad = lane >> 4;
    const int wm = w & 1, wn = w >> 1;

    f32x4 acc[4][4] = {};

    for (int kc = 0; kc < 1024; kc += 64) {
        __syncthreads();
        #pragma unroll
        for (int i = 0; i < 4; i++) {
            int s = (w * 4 + i) * 64 + lane;
            int r = s >> 3, j = s & 7, g = j ^ (r & 7);
            size_t aoff = (size_t)(mt * 128 + r) * 1024 + kc + g * 8;
            size_t boff = (size_t)(nt * 128 + r) * 1024 + kc + g * 8;
            GLOAD_LDS16(Wvh + aoff, Ah  + (size_t)(w * 4 + i) * 512);
            GLOAD_LDS16(Xh  + boff, Bhs + (size_t)(w * 4 + i) * 512);
        }
        __syncthreads();
        #pragma unroll
        for (int kk = 0; kk < 2; kk++) {
            bf16x8 a_h[4], b_h[4];
            const int gi = kk * 4 + quad;
            #pragma unroll
            for (int t = 0; t < 4; t++) {
                int rA = wm * 64 + t * 16 + col;
                a_h[t] = *(const bf16x8*)&Ah[(rA * 8 + (gi ^ (rA & 7))) * 8];
                int rB = wn * 64 + t * 16 + col;
                b_h[t] = *(const bf16x8*)&Bhs[(rB * 8 + (gi ^ (rB & 7))) * 8];
            }
            #pragma unroll
            for (int t = 0; t < 4; t++)
                #pragma unroll
                for (int u = 0; u < 4; u++)
                    acc[t][u] = MFMA16(a_h[t], b_h[u], acc[t][u]);
        }
    }

    #pragma unroll
    for (int t = 0; t < 4; t++) {
        #pragma unroll
        for (int rr = 0; rr < 4; rr++) {
            int ep = mt * 128 + wm * 64 + t * 16 + quad * 4 + rr;
            int head = ep >> 6, e = ep & 63;
            #pragma unroll
            for (int u = 0; u < 4; u++) {
                int lg = nt * 128 + wn * 64 + u * 16 + col;
                int bi = lg >> 11, l = lg & 2047;
                Vt[(((size_t)bi * NHEADS + head) * HD + e) * SEQ + l] = f2bf(acc[t][u][rr]);
            }
        }
    }
}

// ---------------------------------------------------------------------------
// Flash attention: r4's LDS-staged structure (latency hiding via
// global_load_lds + barriers) + r5's DPP/exp2 softmax (VALU pipe), with
// 32 q-rows per wave (2 m-tiles) so K/V fragment DS reads amortize 2x.
// Block = 4 waves = 128 q-rows; 32 chunks of 64 keys.
// ---------------------------------------------------------------------------
__global__ __launch_bounds__(256, 3) void attn_mfma_kernel(
    const float* __restrict__ Qf, const ushort_t* __restrict__ Khi,
    const ushort_t* __restrict__ Klo, const ushort_t* __restrict__ Vt,
    float* __restrict__ out)
{
    __shared__ __align__(16) ushort_t Khs[64 * 64];
    __shared__ __align__(16) ushort_t Kls[64 * 64];
    __shared__ __align__(16) ushort_t Vts[64 * 64];
    __shared__ __align__(16) ushort_t Ps[4][32 * 72];   // per-wave P tile (32 rows)

    const int qt  = blockIdx.x;       // 0..15 (128 q-rows per block)
    const int bn  = blockIdx.y;       // 0..63
    const int tid = threadIdx.x;
    const int w    = tid >> 6;
    const int lane = tid & 63;
    const int col  = lane & 15;
    const int quad = lane >> 4;

    const ushort_t* Kh_g = Khi + (size_t)bn * SEQ * HD;
    const ushort_t* Kl_g = Klo + (size_t)bn * SEQ * HD;
    const ushort_t* Vt_g = Vt  + (size_t)bn * HD * SEQ;

    // ---- Q A-fragments: 2 m-tiles x 2 k-slices, scaled by log2e/8, split hi/lo
    union { bf16x8 v; short s[8]; } qh[2][2], ql[2][2];
    #pragma unroll
    for (int m = 0; m < 2; m++) {
        const int qrow = qt * 128 + w * 32 + m * 16 + col;
        const float* qp = Qf + ((size_t)bn * SEQ + qrow) * HD;
        #pragma unroll
        for (int ks = 0; ks < 2; ks++) {
            float qv[8];
            f32x4 a = *(const f32x4*)(qp + ks * 32 + quad * 8);
            f32x4 b = *(const f32x4*)(qp + ks * 32 + quad * 8 + 4);
            qv[0]=a[0]; qv[1]=a[1]; qv[2]=a[2]; qv[3]=a[3];
            qv[4]=b[0]; qv[5]=b[1]; qv[6]=b[2]; qv[7]=b[3];
            #pragma unroll
            for (int j = 0; j < 8; j++) {
                float xsc = qv[j] * (0.125f * 1.44269504088896f);   // log2e/sqrt(64)
                ushort_t hi = f2bf(xsc);
                ushort_t lo = f2bf(xsc - bf2f(hi));
                qh[m][ks].s[j] = (short)hi;
                ql[m][ks].s[j] = (short)lo;
            }
        }
    }

    f32x4 O[2][4] = {};
    float m_i[2][4] = {{-1e30f,-1e30f,-1e30f,-1e30f},{-1e30f,-1e30f,-1e30f,-1e30f}};
    float l_i[2][4] = {};
    ushort_t* Pw = Ps[w];

    for (int ch = 0; ch < 32; ch++) {
        __syncthreads();   // previous chunk fully consumed
        #pragma unroll
        for (int t = 0; t < 2; t++) {
            int G   = (w * 2 + t) * 64 + lane;          // granule 0..511
            int key = G >> 3;                            // key (K) / e (V)
            int blk = (G & 7) ^ (key & 7);               // swizzled 8-elem block
            size_t koff = (size_t)(ch * 64 + key) * HD + blk * 8;
            size_t voff = (size_t)key * SEQ + ch * 64 + blk * 8;
            GLOAD_LDS16(Kh_g + koff, Khs + (w * 2 + t) * 512);
            GLOAD_LDS16(Kl_g + koff, Kls + (w * 2 + t) * 512);
            GLOAD_LDS16(Vt_g + voff, Vts + (w * 2 + t) * 512);
        }
        __syncthreads();   // staged data visible

        // ---- S = Q K^T: K frags read once, reused across both m-tiles
        f32x4 S[2][4] = {};
        #pragma unroll
        for (int ks = 0; ks < 2; ks++) {
            #pragma unroll
            for (int t = 0; t < 4; t++) {
                int key = t * 16 + col;
                int g = key * 8 + ((ks * 4 + quad) ^ (key & 7));
                bf16x8 kh = *(const bf16x8*)&Khs[g * 8];
                bf16x8 kl = *(const bf16x8*)&Kls[g * 8];
                #pragma unroll
                for (int m = 0; m < 2; m++) {
                    S[m][t] = MFMA16(qh[m][ks].v, kh, S[m][t]);
                    S[m][t] = MFMA16(ql[m][ks].v, kh, S[m][t]);
                    S[m][t] = MFMA16(qh[m][ks].v, kl, S[m][t]);
                }
            }
        }

        // ---- online softmax (exp2 domain), DPP reductions, per m-tile
        float al[2][4];
        #pragma unroll
        for (int m = 0; m < 2; m++) {
            float mnew[4], ps[4];
            #pragma unroll
            for (int r = 0; r < 4; r++) {
                float mx = fmaxf(fmaxf(S[m][0][r], S[m][1][r]), fmaxf(S[m][2][r], S[m][3][r]));
                mx = row_max16(mx);
                mnew[r]   = fmaxf(m_i[m][r], mx);
                al[m][r]  = exp2f(m_i[m][r] - mnew[r]);
                m_i[m][r] = mnew[r];
                ps[r]     = 0.f;
            }
            #pragma unroll
            for (int t = 0; t < 4; t++) {
                #pragma unroll
                for (int r = 0; r < 4; r++) {
                    float p = exp2f(S[m][t][r] - mnew[r]);
                    ps[r] += p;
                    Pw[(m * 16 + quad * 4 + r) * 72 + t * 16 + col] = f2bf(p);
                }
            }
            #pragma unroll
            for (int r = 0; r < 4; r++) {
                l_i[m][r] = l_i[m][r] * al[m][r] + row_sum16(ps[r]);
                O[m][0][r] *= al[m][r]; O[m][1][r] *= al[m][r];
                O[m][2][r] *= al[m][r]; O[m][3][r] *= al[m][r];
            }
        }

        // ---- O += P V: V frags read once, reused across both m-tiles
        #pragma unroll
        for (int ks = 0; ks < 2; ks++) {
            bf16x8 pf0 = *(const bf16x8*)&Pw[(col)      * 72 + ks * 32 + quad * 8];
            bf16x8 pf1 = *(const bf16x8*)&Pw[(16 + col) * 72 + ks * 32 + quad * 8];
            #pragma unroll
            for (int t = 0; t < 4; t++) {
                int e = t * 16 + col;
                int g = e * 8 + ((ks * 4 + quad) ^ (e & 7));
                bf16x8 vf = *(const bf16x8*)&Vts[g * 8];
                O[0][t] = MFMA16(pf0, vf, O[0][t]);
                O[1][t] = MFMA16(pf1, vf, O[1][t]);
            }
        }
    }

    // ---- epilogue: out[b][l][n*64+e] = O / l
    const int b = bn >> 4, n = bn & 15;
    #pragma unroll
    for (int m = 0; m < 2; m++) {
        #pragma unroll
        for (int t = 0; t < 4; t++) {
            #pragma unroll
            for (int r = 0; r < 4; r++) {
                int l = qt * 128 + w * 32 + m * 16 + quad * 4 + r;
                out[((size_t)(b * SEQ + l)) * (NHEADS * HD) + n * HD + t * 16 + col]
                    = O[m][t][r] / l_i[m][r];
            }
        }
    }
}

// ---------------------------------------------------------------------------
extern "C" void kernel_launch(void* const* d_in, const int* in_sizes, int n_in,
                              void* d_out, int out_size, void* d_ws, size_t ws_size,
                              hipStream_t stream) {
    const float* x  = (const float*)d_in[0];
    const float* wk = (const float*)d_in[1];
    const float* wq = (const float*)d_in[2];
    const float* wv = (const float*)d_in[3];
    float* out = (float*)d_out;

    // ws layout (111 MB): Xh | Xl (aliased by Vt after proj_qk) | Bqh | Bql | Bvh | Qf | Khi | Klo
    ushort_t* Xh  = (ushort_t*)d_ws;
    ushort_t* Xl  = Xh + NM;
    ushort_t* Vt  = Xl;                      // alias: Xl dead once proj_qk finishes
    ushort_t* Bqh = Xl + NM;                 // [2048][1024]
    ushort_t* Bql = Bqh + 2097152;
    ushort_t* Bvh = Bql + 2097152;           // [1024][1024]
    float*    Qf  = (float*)(Bvh + 1048576);
    ushort_t* Khi = (ushort_t*)(Qf + NM);
    ushort_t* Klo = Khi + NM;

    convert_x<<<2048, 256, 0, stream>>>(x, Xh, Xl);
    convert_w<<<768, 256, 0, stream>>>(wk, wq, wv, Bqh, Bql, Bvh);
    proj_qk<<<dim3(64, 16), 256, 0, stream>>>(Xh, Xl, Bqh, Bql, Qf, Khi, Klo);
    proj_v<<<dim3(8, 64), 256, 0, stream>>>(Bvh, Xh, Vt);
    attn_mfma_kernel<<<dim3(16, 64), 256, 0, stream>>>(Qf, Khi, Klo, Vt, out);
}

// Round 7
// 421.102 us; speedup vs baseline: 2.0648x; 1.0415x over previous
//
#include <hip/hip_runtime.h>
#include <math.h>

#define DIMX   1024
#define NHEADS 16
#define HD     64
#define BATCH  4
#define SEQ    2048
#define NM     (BATCH * NHEADS * SEQ * HD)   // 8388608 elems per Q/K/V tensor

typedef unsigned short ushort_t;
typedef __attribute__((ext_vector_type(8))) short bf16x8;
typedef __attribute__((ext_vector_type(4))) float f32x4;

#define MFMA16(a, b, c) __builtin_amdgcn_mfma_f32_16x16x32_bf16(a, b, c, 0, 0, 0)

// round-to-nearest-even fp32 -> bf16 bits
__device__ __forceinline__ ushort_t f2bf(float x) {
    unsigned u = __float_as_uint(x);
    u += 0x7fffu + ((u >> 16) & 1u);
    return (ushort_t)(u >> 16);
}
__device__ __forceinline__ float bf2f(ushort_t h) {
    return __uint_as_float(((unsigned)h) << 16);
}

// raw v_exp_f32 (no ocml edge-case wrapper) — guarded
__device__ __forceinline__ float fast_exp2(float x) {
#if __has_builtin(__builtin_amdgcn_exp2f)
    return __builtin_amdgcn_exp2f(x);
#else
    return exp2f(x);
#endif
}

// async global->LDS, 16B per lane; LDS base wave-uniform (HW adds lane*16)
#define GLOAD_LDS16(g, l) \
    __builtin_amdgcn_global_load_lds((const __attribute__((address_space(1))) unsigned int*)(g), \
                                     (__attribute__((address_space(3))) unsigned int*)(l), 16, 0, 0)

// DPP 16-lane butterfly reductions (VALU pipe, not DS) — verified r5/r6.
template<int CTRL>
__device__ __forceinline__ float dpp_mov(float x) {
    return __int_as_float(__builtin_amdgcn_update_dpp(0, __float_as_int(x), CTRL, 0xF, 0xF, true));
}
__device__ __forceinline__ float row_max16(float x) {
    x = fmaxf(x, dpp_mov<0xB1>(x));
    x = fmaxf(x, dpp_mov<0x4E>(x));
    x = fmaxf(x, dpp_mov<0x141>(x));
    x = fmaxf(x, dpp_mov<0x140>(x));
    return x;
}
__device__ __forceinline__ float row_sum16(float x) {
    x += dpp_mov<0xB1>(x);
    x += dpp_mov<0x4E>(x);
    x += dpp_mov<0x141>(x);
    x += dpp_mov<0x140>(x);
    return x;
}

// ---------------------------------------------------------------------------
// convert_x: split x fp32 -> Xhi, Xlo bf16.  (unchanged)
// ---------------------------------------------------------------------------
__global__ __launch_bounds__(256) void convert_x(
    const float* __restrict__ x, ushort_t* __restrict__ Xh, ushort_t* __restrict__ Xl)
{
    int i = blockIdx.x * 256 + threadIdx.x;
    #pragma unroll
    for (int t = 0; t < 4; t++) {
        int idx = t * 524288 + i;
        f32x4 v = ((const f32x4*)x)[idx];
        ushort4 hi, lo;
        hi.x = f2bf(v[0]); lo.x = f2bf(v[0] - bf2f(hi.x));
        hi.y = f2bf(v[1]); lo.y = f2bf(v[1] - bf2f(hi.y));
        hi.z = f2bf(v[2]); lo.z = f2bf(v[2] - bf2f(hi.z));
        hi.w = f2bf(v[3]); lo.w = f2bf(v[3] - bf2f(hi.w));
        ((ushort4*)Xh)[idx] = hi;
        ((ushort4*)Xl)[idx] = lo;
    }
}

// ---------------------------------------------------------------------------
// convert_w: transpose w[n][d][e] -> Wt[e'][d], split hi/lo bf16. (unchanged)
// ---------------------------------------------------------------------------
__global__ __launch_bounds__(256) void convert_w(
    const float* __restrict__ wk, const float* __restrict__ wq, const float* __restrict__ wv,
    ushort_t* __restrict__ Bqh, ushort_t* __restrict__ Bql, ushort_t* __restrict__ Bvh)
{
    __shared__ float Ts[64][65];
    const int bid = blockIdx.x;
    const int mat = bid >> 8;
    const int rem = bid & 255;
    const int n  = rem >> 4;
    const int dt = rem & 15;
    const float* w = (mat == 0) ? wq : (mat == 1) ? wk : wv;
    const int tid = threadIdx.x;

    #pragma unroll
    for (int t = 0; t < 16; t++) {
        int i = tid + t * 256;
        int r = i >> 6, e = i & 63;
        Ts[r][e] = w[((size_t)n * 1024 + dt * 64 + r) * 64 + e];
    }
    __syncthreads();
    #pragma unroll
    for (int t = 0; t < 16; t++) {
        int i = tid + t * 256;
        int e = i >> 6, r = i & 63;
        float v = Ts[r][e];
        ushort_t hi = f2bf(v);
        size_t o = (size_t)(n * 64 + e) * 1024 + dt * 64 + r;
        if (mat < 2) {
            Bqh[(size_t)mat * 1048576 + o] = hi;
            Bql[(size_t)mat * 1048576 + o] = f2bf(v - bf2f(hi));
        } else {
            Bvh[o] = hi;
        }
    }
}

// ---------------------------------------------------------------------------
// proj_qk: 3-pass split-bf16 MFMA GEMM. (unchanged)
// ---------------------------------------------------------------------------
__global__ __launch_bounds__(256) void proj_qk(
    const ushort_t* __restrict__ Xh, const ushort_t* __restrict__ Xl,
    const ushort_t* __restrict__ Bh, const ushort_t* __restrict__ Bl,
    float* __restrict__ Qf, ushort_t* __restrict__ Khi, ushort_t* __restrict__ Klo)
{
    __shared__ __align__(16) ushort_t Ah[128 * 64];
    __shared__ __align__(16) ushort_t Al[128 * 64];
    __shared__ __align__(16) ushort_t Bhs[128 * 64];
    __shared__ __align__(16) ushort_t Bls[128 * 64];

    const int mt = blockIdx.x, nt = blockIdx.y;
    const int tid = threadIdx.x;
    const int w = tid >> 6, lane = tid & 63, col = lane & 15, quad = lane >> 4;
    const int wm = w & 1, wn = w >> 1;

    f32x4 acc[4][4] = {};

    for (int kc = 0; kc < 1024; kc += 64) {
        __syncthreads();
        #pragma unroll
        for (int i = 0; i < 4; i++) {
            int s = (w * 4 + i) * 64 + lane;
            int r = s >> 3, j = s & 7, g = j ^ (r & 7);
            size_t aoff = (size_t)(mt * 128 + r) * 1024 + kc + g * 8;
            size_t boff = (size_t)(nt * 128 + r) * 1024 + kc + g * 8;
            GLOAD_LDS16(Xh + aoff, Ah  + (size_t)(w * 4 + i) * 512);
            GLOAD_LDS16(Xl + aoff, Al  + (size_t)(w * 4 + i) * 512);
            GLOAD_LDS16(Bh + boff, Bhs + (size_t)(w * 4 + i) * 512);
            GLOAD_LDS16(Bl + boff, Bls + (size_t)(w * 4 + i) * 512);
        }
        __syncthreads();
        #pragma unroll
        for (int kk = 0; kk < 2; kk++) {
            bf16x8 a_h[4], a_l[4], b_h[4], b_l[4];
            const int gi = kk * 4 + quad;
            #pragma unroll
            for (int t = 0; t < 4; t++) {
                int rA = wm * 64 + t * 16 + col;
                int jA = gi ^ (rA & 7);
                a_h[t] = *(const bf16x8*)&Ah[(rA * 8 + jA) * 8];
                a_l[t] = *(const bf16x8*)&Al[(rA * 8 + jA) * 8];
                int rB = wn * 64 + t * 16 + col;
                int jB = gi ^ (rB & 7);
                b_h[t] = *(const bf16x8*)&Bhs[(rB * 8 + jB) * 8];
                b_l[t] = *(const bf16x8*)&Bls[(rB * 8 + jB) * 8];
            }
            #pragma unroll
            for (int t = 0; t < 4; t++)
                #pragma unroll
                for (int u = 0; u < 4; u++) {
                    acc[t][u] = MFMA16(a_h[t], b_h[u], acc[t][u]);
                    acc[t][u] = MFMA16(a_l[t], b_h[u], acc[t][u]);
                    acc[t][u] = MFMA16(a_h[t], b_l[u], acc[t][u]);
                }
        }
    }

    const bool isQ = (nt < 8);
    #pragma unroll
    for (int t = 0; t < 4; t++) {
        #pragma unroll
        for (int u = 0; u < 4; u++) {
            int np = nt * 128 + wn * 64 + u * 16 + col;
            int head = (np >> 6) & 15, e = np & 63;
            #pragma unroll
            for (int rr = 0; rr < 4; rr++) {
                int mm = mt * 128 + wm * 64 + t * 16 + quad * 4 + rr;
                int bi = mm >> 11, l = mm & 2047;
                size_t base = (((size_t)bi * NHEADS + head) * SEQ + l) * HD + e;
                float v = acc[t][u][rr];
                if (isQ) {
                    Qf[base] = v;
                } else {
                    ushort_t hi = f2bf(v);
                    Khi[base] = hi;
                    Klo[base] = f2bf(v - bf2f(hi));
                }
            }
        }
    }
}

// ---------------------------------------------------------------------------
// proj_v: 1-pass bf16, operand-swapped for transposed-V output. (unchanged)
// ---------------------------------------------------------------------------
__global__ __launch_bounds__(256) void proj_v(
    const ushort_t* __restrict__ Wvh, const ushort_t* __restrict__ Xh,
    ushort_t* __restrict__ Vt)
{
    __shared__ __align__(16) ushort_t Ah[128 * 64];
    __shared__ __align__(16) ushort_t Bhs[128 * 64];

    const int mt = blockIdx.x, nt = blockIdx.y;
    const int tid = threadIdx.x;
    const int w = tid >> 6, lane = tid & 63, col = lane & 15, quad = lane >> 4;
    const int wm = w & 1, wn = w >> 1;

    f32x4 acc[4][4] = {};

    for (int kc = 0; kc < 1024; kc += 64) {
        __syncthreads();
        #pragma unroll
        for (int i = 0; i < 4; i++) {
            int s = (w * 4 + i) * 64 + lane;
            int r = s >> 3, j = s & 7, g = j ^ (r & 7);
            size_t aoff = (size_t)(mt * 128 + r) * 1024 + kc + g * 8;
            size_t boff = (size_t)(nt * 128 + r) * 1024 + kc + g * 8;
            GLOAD_LDS16(Wvh + aoff, Ah  + (size_t)(w * 4 + i) * 512);
            GLOAD_LDS16(Xh  + boff, Bhs + (size_t)(w * 4 + i) * 512);
        }
        __syncthreads();
        #pragma unroll
        for (int kk = 0; kk < 2; kk++) {
            bf16x8 a_h[4], b_h[4];
            const int gi = kk * 4 + quad;
            #pragma unroll
            for (int t = 0; t < 4; t++) {
                int rA = wm * 64 + t * 16 + col;
                a_h[t] = *(const bf16x8*)&Ah[(rA * 8 + (gi ^ (rA & 7))) * 8];
                int rB = wn * 64 + t * 16 + col;
                b_h[t] = *(const bf16x8*)&Bhs[(rB * 8 + (gi ^ (rB & 7))) * 8];
            }
            #pragma unroll
            for (int t = 0; t < 4; t++)
                #pragma unroll
                for (int u = 0; u < 4; u++)
                    acc[t][u] = MFMA16(a_h[t], b_h[u], acc[t][u]);
        }
    }

    #pragma unroll
    for (int t = 0; t < 4; t++) {
        #pragma unroll
        for (int rr = 0; rr < 4; rr++) {
            int ep = mt * 128 + wm * 64 + t * 16 + quad * 4 + rr;
            int head = ep >> 6, e = ep & 63;
            #pragma unroll
            for (int u = 0; u < 4; u++) {
                int lg = nt * 128 + wn * 64 + u * 16 + col;
                int bi = lg >> 11, l = lg & 2047;
                Vt[(((size_t)bi * NHEADS + head) * HD + e) * SEQ + l] = f2bf(acc[t][u][rr]);
            }
        }
    }
}

// ---------------------------------------------------------------------------
// Flash attention: staged (r6 structure), 64 q-rows per wave (m=4) so K/V
// fragment DS reads amortize 4x. Raw v_exp_f32; l-sum deferred to epilogue
// (per-lane partial L, alpha-rescaled per chunk — exact since alpha is
// row-uniform). Block = 4 waves = 256 q-rows; 32 chunks of 64 keys.
// ---------------------------------------------------------------------------
__global__ __launch_bounds__(256, 2) void attn_mfma_kernel(
    const float* __restrict__ Qf, const ushort_t* __restrict__ Khi,
    const ushort_t* __restrict__ Klo, const ushort_t* __restrict__ Vt,
    float* __restrict__ out)
{
    __shared__ __align__(16) ushort_t Khs[64 * 64];
    __shared__ __align__(16) ushort_t Kls[64 * 64];
    __shared__ __align__(16) ushort_t Vts[64 * 64];
    __shared__ __align__(16) ushort_t Ps[4][64 * 72];   // per-wave P tile (64 rows)

    const int qt  = blockIdx.x;       // 0..7 (256 q-rows per block)
    const int bn  = blockIdx.y;       // 0..63
    const int tid = threadIdx.x;
    const int w    = tid >> 6;
    const int lane = tid & 63;
    const int col  = lane & 15;
    const int quad = lane >> 4;

    const ushort_t* Kh_g = Khi + (size_t)bn * SEQ * HD;
    const ushort_t* Kl_g = Klo + (size_t)bn * SEQ * HD;
    const ushort_t* Vt_g = Vt  + (size_t)bn * HD * SEQ;

    // ---- Q A-fragments: 4 m-tiles x 2 k-slices, scaled by log2e/8, split hi/lo
    union { bf16x8 v; short s[8]; } qh[4][2], ql[4][2];
    #pragma unroll
    for (int m = 0; m < 4; m++) {
        const int qrow = qt * 256 + w * 64 + m * 16 + col;
        const float* qp = Qf + ((size_t)bn * SEQ + qrow) * HD;
        #pragma unroll
        for (int ks = 0; ks < 2; ks++) {
            float qv[8];
            f32x4 a = *(const f32x4*)(qp + ks * 32 + quad * 8);
            f32x4 b = *(const f32x4*)(qp + ks * 32 + quad * 8 + 4);
            qv[0]=a[0]; qv[1]=a[1]; qv[2]=a[2]; qv[3]=a[3];
            qv[4]=b[0]; qv[5]=b[1]; qv[6]=b[2]; qv[7]=b[3];
            #pragma unroll
            for (int j = 0; j < 8; j++) {
                float xsc = qv[j] * (0.125f * 1.44269504088896f);   // log2e/sqrt(64)
                ushort_t hi = f2bf(xsc);
                ushort_t lo = f2bf(xsc - bf2f(hi));
                qh[m][ks].s[j] = (short)hi;
                ql[m][ks].s[j] = (short)lo;
            }
        }
    }

    f32x4 O[4][4] = {};
    float m_i[4][4] = {{-1e30f,-1e30f,-1e30f,-1e30f},{-1e30f,-1e30f,-1e30f,-1e30f},
                       {-1e30f,-1e30f,-1e30f,-1e30f},{-1e30f,-1e30f,-1e30f,-1e30f}};
    float L[4][4] = {};               // per-lane partial denominators
    ushort_t* Pw = Ps[w];

    for (int ch = 0; ch < 32; ch++) {
        __syncthreads();   // previous chunk fully consumed
        #pragma unroll
        for (int t = 0; t < 2; t++) {
            int G   = (w * 2 + t) * 64 + lane;          // granule 0..511
            int key = G >> 3;                            // key (K) / e (V)
            int blk = (G & 7) ^ (key & 7);               // swizzled 8-elem block
            size_t koff = (size_t)(ch * 64 + key) * HD + blk * 8;
            size_t voff = (size_t)key * SEQ + ch * 64 + blk * 8;
            GLOAD_LDS16(Kh_g + koff, Khs + (w * 2 + t) * 512);
            GLOAD_LDS16(Kl_g + koff, Kls + (w * 2 + t) * 512);
            GLOAD_LDS16(Vt_g + voff, Vts + (w * 2 + t) * 512);
        }
        __syncthreads();   // staged data visible

        // ---- S = Q K^T: K frags read once, reused across all 4 m-tiles
        f32x4 S[4][4] = {};
        #pragma unroll
        for (int ks = 0; ks < 2; ks++) {
            #pragma unroll
            for (int t = 0; t < 4; t++) {
                int key = t * 16 + col;
                int g = key * 8 + ((ks * 4 + quad) ^ (key & 7));
                bf16x8 kh = *(const bf16x8*)&Khs[g * 8];
                bf16x8 kl = *(const bf16x8*)&Kls[g * 8];
                #pragma unroll
                for (int m = 0; m < 4; m++) {
                    S[m][t] = MFMA16(qh[m][ks].v, kh, S[m][t]);
                    S[m][t] = MFMA16(ql[m][ks].v, kh, S[m][t]);
                    S[m][t] = MFMA16(qh[m][ks].v, kl, S[m][t]);
                }
            }
        }

        // ---- online softmax (exp2 domain), DPP max; l-sum deferred
        #pragma unroll
        for (int m = 0; m < 4; m++) {
            float mnew[4], al[4], ps[4];
            #pragma unroll
            for (int r = 0; r < 4; r++) {
                float mx = fmaxf(fmaxf(S[m][0][r], S[m][1][r]), fmaxf(S[m][2][r], S[m][3][r]));
                mx = row_max16(mx);
                mnew[r]   = fmaxf(m_i[m][r], mx);
                al[r]     = fast_exp2(m_i[m][r] - mnew[r]);
                m_i[m][r] = mnew[r];
                ps[r]     = 0.f;
            }
            #pragma unroll
            for (int t = 0; t < 4; t++) {
                #pragma unroll
                for (int r = 0; r < 4; r++) {
                    float p = fast_exp2(S[m][t][r] - mnew[r]);
                    ps[r] += p;
                    Pw[(m * 16 + quad * 4 + r) * 72 + t * 16 + col] = f2bf(p);
                }
            }
            #pragma unroll
            for (int r = 0; r < 4; r++) {
                L[m][r] = L[m][r] * al[r] + ps[r];     // per-lane partial; exact (al row-uniform)
                O[m][0][r] *= al[r]; O[m][1][r] *= al[r];
                O[m][2][r] *= al[r]; O[m][3][r] *= al[r];
            }
        }

        // ---- O += P V: V frags read once, reused across all 4 m-tiles
        #pragma unroll
        for (int ks = 0; ks < 2; ks++) {
            bf16x8 pf[4];
            #pragma unroll
            for (int m = 0; m < 4; m++)
                pf[m] = *(const bf16x8*)&Pw[(m * 16 + col) * 72 + ks * 32 + quad * 8];
            #pragma unroll
            for (int t = 0; t < 4; t++) {
                int e = t * 16 + col;
                int g = e * 8 + ((ks * 4 + quad) ^ (e & 7));
                bf16x8 vf = *(const bf16x8*)&Vts[g * 8];
                #pragma unroll
                for (int m = 0; m < 4; m++)
                    O[m][t] = MFMA16(pf[m], vf, O[m][t]);
            }
        }
    }

    // ---- epilogue: finish l (one DPP sum per row), out = O / l
    const int b = bn >> 4, n = bn & 15;
    #pragma unroll
    for (int m = 0; m < 4; m++) {
        float lrow[4];
        #pragma unroll
        for (int r = 0; r < 4; r++) lrow[r] = row_sum16(L[m][r]);
        #pragma unroll
        for (int t = 0; t < 4; t++) {
            #pragma unroll
            for (int r = 0; r < 4; r++) {
                int l = qt * 256 + w * 64 + m * 16 + quad * 4 + r;
                out[((size_t)(b * SEQ + l)) * (NHEADS * HD) + n * HD + t * 16 + col]
                    = O[m][t][r] / lrow[r];
            }
        }
    }
}

// ---------------------------------------------------------------------------
extern "C" void kernel_launch(void* const* d_in, const int* in_sizes, int n_in,
                              void* d_out, int out_size, void* d_ws, size_t ws_size,
                              hipStream_t stream) {
    const float* x  = (const float*)d_in[0];
    const float* wk = (const float*)d_in[1];
    const float* wq = (const float*)d_in[2];
    const float* wv = (const float*)d_in[3];
    float* out = (float*)d_out;

    // ws layout (111 MB): Xh | Xl (aliased by Vt after proj_qk) | Bqh | Bql | Bvh | Qf | Khi | Klo
    ushort_t* Xh  = (ushort_t*)d_ws;
    ushort_t* Xl  = Xh + NM;
    ushort_t* Vt  = Xl;                      // alias: Xl dead once proj_qk finishes
    ushort_t* Bqh = Xl + NM;                 // [2048][1024]
    ushort_t* Bql = Bqh + 2097152;
    ushort_t* Bvh = Bql + 2097152;           // [1024][1024]
    float*    Qf  = (float*)(Bvh + 1048576);
    ushort_t* Khi = (ushort_t*)(Qf + NM);
    ushort_t* Klo = Khi + NM;

    convert_x<<<2048, 256, 0, stream>>>(x, Xh, Xl);
    convert_w<<<768, 256, 0, stream>>>(wk, wq, wv, Bqh, Bql, Bvh);
    proj_qk<<<dim3(64, 16), 256, 0, stream>>>(Xh, Xl, Bqh, Bql, Qf, Khi, Klo);
    proj_v<<<dim3(8, 64), 256, 0, stream>>>(Bvh, Xh, Vt);
    attn_mfma_kernel<<<dim3(8, 64), 256, 0, stream>>>(Qf, Khi, Klo, Vt, out);
}

// Round 8
// 383.293 us; speedup vs baseline: 2.2685x; 1.0986x over previous
//
#include <hip/hip_runtime.h>
#include <math.h>

#define DIMX   1024
#define NHEADS 16
#define HD     64
#define BATCH  4
#define SEQ    2048
#define NM     (BATCH * NHEADS * SEQ * HD)   // 8388608 elems per Q/K/V tensor

typedef unsigned short ushort_t;
typedef __attribute__((ext_vector_type(8))) short bf16x8;
typedef __attribute__((ext_vector_type(4))) short bf16x4;
typedef __attribute__((ext_vector_type(4))) float f32x4;

#define MFMA16(a, b, c) __builtin_amdgcn_mfma_f32_16x16x32_bf16(a, b, c, 0, 0, 0)

// K=16 bf16 MFMA (A,B = 4 bf16 each). gfx90a+ "_1k" builtin; asm fallback.
#if __has_builtin(__builtin_amdgcn_mfma_f32_16x16x16bf16_1k)
#define MFMA_PV(a, b, c) __builtin_amdgcn_mfma_f32_16x16x16bf16_1k(a, b, c, 0, 0, 0)
#else
static __device__ __forceinline__ f32x4 mfma_pv_asm(bf16x4 a, bf16x4 b, f32x4 c) {
    asm("v_mfma_f32_16x16x16_bf16 %0, %1, %2, %0" : "+v"(c) : "v"(a), "v"(b));
    return c;
}
#define MFMA_PV(a, b, c) mfma_pv_asm(a, b, c)
#endif

// round-to-nearest-even fp32 -> bf16 bits
__device__ __forceinline__ ushort_t f2bf(float x) {
    unsigned u = __float_as_uint(x);
    u += 0x7fffu + ((u >> 16) & 1u);
    return (ushort_t)(u >> 16);
}
__device__ __forceinline__ float bf2f(ushort_t h) {
    return __uint_as_float(((unsigned)h) << 16);
}

// raw v_exp_f32 (no ocml edge-case wrapper) — guarded
__device__ __forceinline__ float fast_exp2(float x) {
#if __has_builtin(__builtin_amdgcn_exp2f)
    return __builtin_amdgcn_exp2f(x);
#else
    return exp2f(x);
#endif
}

// async global->LDS, 16B per lane; LDS base wave-uniform (HW adds lane*16)
#define GLOAD_LDS16(g, l) \
    __builtin_amdgcn_global_load_lds((const __attribute__((address_space(1))) unsigned int*)(g), \
                                     (__attribute__((address_space(3))) unsigned int*)(l), 16, 0, 0)

// ---------------------------------------------------------------------------
// convert_x: split x fp32 -> Xhi, Xlo bf16.  (unchanged)
// ---------------------------------------------------------------------------
__global__ __launch_bounds__(256) void convert_x(
    const float* __restrict__ x, ushort_t* __restrict__ Xh, ushort_t* __restrict__ Xl)
{
    int i = blockIdx.x * 256 + threadIdx.x;
    #pragma unroll
    for (int t = 0; t < 4; t++) {
        int idx = t * 524288 + i;
        f32x4 v = ((const f32x4*)x)[idx];
        ushort4 hi, lo;
        hi.x = f2bf(v[0]); lo.x = f2bf(v[0] - bf2f(hi.x));
        hi.y = f2bf(v[1]); lo.y = f2bf(v[1] - bf2f(hi.y));
        hi.z = f2bf(v[2]); lo.z = f2bf(v[2] - bf2f(hi.z));
        hi.w = f2bf(v[3]); lo.w = f2bf(v[3] - bf2f(hi.w));
        ((ushort4*)Xh)[idx] = hi;
        ((ushort4*)Xl)[idx] = lo;
    }
}

// ---------------------------------------------------------------------------
// convert_w: transpose w[n][d][e] -> Wt[e'][d], split hi/lo bf16. (unchanged)
// ---------------------------------------------------------------------------
__global__ __launch_bounds__(256) void convert_w(
    const float* __restrict__ wk, const float* __restrict__ wq, const float* __restrict__ wv,
    ushort_t* __restrict__ Bqh, ushort_t* __restrict__ Bql, ushort_t* __restrict__ Bvh)
{
    __shared__ float Ts[64][65];
    const int bid = blockIdx.x;
    const int mat = bid >> 8;
    const int rem = bid & 255;
    const int n  = rem >> 4;
    const int dt = rem & 15;
    const float* w = (mat == 0) ? wq : (mat == 1) ? wk : wv;
    const int tid = threadIdx.x;

    #pragma unroll
    for (int t = 0; t < 16; t++) {
        int i = tid + t * 256;
        int r = i >> 6, e = i & 63;
        Ts[r][e] = w[((size_t)n * 1024 + dt * 64 + r) * 64 + e];
    }
    __syncthreads();
    #pragma unroll
    for (int t = 0; t < 16; t++) {
        int i = tid + t * 256;
        int e = i >> 6, r = i & 63;
        float v = Ts[r][e];
        ushort_t hi = f2bf(v);
        size_t o = (size_t)(n * 64 + e) * 1024 + dt * 64 + r;
        if (mat < 2) {
            Bqh[(size_t)mat * 1048576 + o] = hi;
            Bql[(size_t)mat * 1048576 + o] = f2bf(v - bf2f(hi));
        } else {
            Bvh[o] = hi;
        }
    }
}

// ---------------------------------------------------------------------------
// proj_qk: 3-pass split-bf16 MFMA GEMM. (unchanged)
// ---------------------------------------------------------------------------
__global__ __launch_bounds__(256) void proj_qk(
    const ushort_t* __restrict__ Xh, const ushort_t* __restrict__ Xl,
    const ushort_t* __restrict__ Bh, const ushort_t* __restrict__ Bl,
    float* __restrict__ Qf, ushort_t* __restrict__ Khi, ushort_t* __restrict__ Klo)
{
    __shared__ __align__(16) ushort_t Ah[128 * 64];
    __shared__ __align__(16) ushort_t Al[128 * 64];
    __shared__ __align__(16) ushort_t Bhs[128 * 64];
    __shared__ __align__(16) ushort_t Bls[128 * 64];

    const int mt = blockIdx.x, nt = blockIdx.y;
    const int tid = threadIdx.x;
    const int w = tid >> 6, lane = tid & 63, col = lane & 15, quad = lane >> 4;
    const int wm = w & 1, wn = w >> 1;

    f32x4 acc[4][4] = {};

    for (int kc = 0; kc < 1024; kc += 64) {
        __syncthreads();
        #pragma unroll
        for (int i = 0; i < 4; i++) {
            int s = (w * 4 + i) * 64 + lane;
            int r = s >> 3, j = s & 7, g = j ^ (r & 7);
            size_t aoff = (size_t)(mt * 128 + r) * 1024 + kc + g * 8;
            size_t boff = (size_t)(nt * 128 + r) * 1024 + kc + g * 8;
            GLOAD_LDS16(Xh + aoff, Ah  + (size_t)(w * 4 + i) * 512);
            GLOAD_LDS16(Xl + aoff, Al  + (size_t)(w * 4 + i) * 512);
            GLOAD_LDS16(Bh + boff, Bhs + (size_t)(w * 4 + i) * 512);
            GLOAD_LDS16(Bl + boff, Bls + (size_t)(w * 4 + i) * 512);
        }
        __syncthreads();
        #pragma unroll
        for (int kk = 0; kk < 2; kk++) {
            bf16x8 a_h[4], a_l[4], b_h[4], b_l[4];
            const int gi = kk * 4 + quad;
            #pragma unroll
            for (int t = 0; t < 4; t++) {
                int rA = wm * 64 + t * 16 + col;
                int jA = gi ^ (rA & 7);
                a_h[t] = *(const bf16x8*)&Ah[(rA * 8 + jA) * 8];
                a_l[t] = *(const bf16x8*)&Al[(rA * 8 + jA) * 8];
                int rB = wn * 64 + t * 16 + col;
                int jB = gi ^ (rB & 7);
                b_h[t] = *(const bf16x8*)&Bhs[(rB * 8 + jB) * 8];
                b_l[t] = *(const bf16x8*)&Bls[(rB * 8 + jB) * 8];
            }
            #pragma unroll
            for (int t = 0; t < 4; t++)
                #pragma unroll
                for (int u = 0; u < 4; u++) {
                    acc[t][u] = MFMA16(a_h[t], b_h[u], acc[t][u]);
                    acc[t][u] = MFMA16(a_l[t], b_h[u], acc[t][u]);
                    acc[t][u] = MFMA16(a_h[t], b_l[u], acc[t][u]);
                }
        }
    }

    const bool isQ = (nt < 8);
    #pragma unroll
    for (int t = 0; t < 4; t++) {
        #pragma unroll
        for (int u = 0; u < 4; u++) {
            int np = nt * 128 + wn * 64 + u * 16 + col;
            int head = (np >> 6) & 15, e = np & 63;
            #pragma unroll
            for (int rr = 0; rr < 4; rr++) {
                int mm = mt * 128 + wm * 64 + t * 16 + quad * 4 + rr;
                int bi = mm >> 11, l = mm & 2047;
                size_t base = (((size_t)bi * NHEADS + head) * SEQ + l) * HD + e;
                float v = acc[t][u][rr];
                if (isQ) {
                    Qf[base] = v;
                } else {
                    ushort_t hi = f2bf(v);
                    Khi[base] = hi;
                    Klo[base] = f2bf(v - bf2f(hi));
                }
            }
        }
    }
}

// ---------------------------------------------------------------------------
// proj_v: 1-pass bf16, operand-swapped for transposed-V output. (unchanged)
// ---------------------------------------------------------------------------
__global__ __launch_bounds__(256) void proj_v(
    const ushort_t* __restrict__ Wvh, const ushort_t* __restrict__ Xh,
    ushort_t* __restrict__ Vt)
{
    __shared__ __align__(16) ushort_t Ah[128 * 64];
    __shared__ __align__(16) ushort_t Bhs[128 * 64];

    const int mt = blockIdx.x, nt = blockIdx.y;
    const int tid = threadIdx.x;
    const int w = tid >> 6, lane = tid & 63, col = lane & 15, quad = lane >> 4;
    const int wm = w & 1, wn = w >> 1;

    f32x4 acc[4][4] = {};

    for (int kc = 0; kc < 1024; kc += 64) {
        __syncthreads();
        #pragma unroll
        for (int i = 0; i < 4; i++) {
            int s = (w * 4 + i) * 64 + lane;
            int r = s >> 3, j = s & 7, g = j ^ (r & 7);
            size_t aoff = (size_t)(mt * 128 + r) * 1024 + kc + g * 8;
            size_t boff = (size_t)(nt * 128 + r) * 1024 + kc + g * 8;
            GLOAD_LDS16(Wvh + aoff, Ah  + (size_t)(w * 4 + i) * 512);
            GLOAD_LDS16(Xh  + boff, Bhs + (size_t)(w * 4 + i) * 512);
        }
        __syncthreads();
        #pragma unroll
        for (int kk = 0; kk < 2; kk++) {
            bf16x8 a_h[4], b_h[4];
            const int gi = kk * 4 + quad;
            #pragma unroll
            for (int t = 0; t < 4; t++) {
                int rA = wm * 64 + t * 16 + col;
                a_h[t] = *(const bf16x8*)&Ah[(rA * 8 + (gi ^ (rA & 7))) * 8];
                int rB = wn * 64 + t * 16 + col;
                b_h[t] = *(const bf16x8*)&Bhs[(rB * 8 + (gi ^ (rB & 7))) * 8];
            }
            #pragma unroll
            for (int t = 0; t < 4; t++)
                #pragma unroll
                for (int u = 0; u < 4; u++)
                    acc[t][u] = MFMA16(a_h[t], b_h[u], acc[t][u]);
        }
    }

    #pragma unroll
    for (int t = 0; t < 4; t++) {
        #pragma unroll
        for (int rr = 0; rr < 4; rr++) {
            int ep = mt * 128 + wm * 64 + t * 16 + quad * 4 + rr;
            int head = ep >> 6, e = ep & 63;
            #pragma unroll
            for (int u = 0; u < 4; u++) {
                int lg = nt * 128 + wn * 64 + u * 16 + col;
                int bi = lg >> 11, l = lg & 2047;
                Vt[(((size_t)bi * NHEADS + head) * HD + e) * SEQ + l] = f2bf(acc[t][u][rr]);
            }
        }
    }
}

// ---------------------------------------------------------------------------
// Flash attention, operand-swapped (round 8):
//   S^T = K·Q^T (swap MFMA args; same LDS reads) -> scores land at
//   (qrow=lane&15, key=quad*4+reg) == the B-operand layout of a K=16 MFMA.
//   P therefore feeds O^T = V^T·P^T straight from registers: NO P LDS
//   round-trip, NO DPP row reductions (softmax state is one scalar per
//   lane per m-tile; cross-quad combine = 2 shuffles). O^T C-layout has
//   qrow=lane&15, e=quad*4+reg -> alpha rescale is per-lane scalar, and
//   the epilogue writes contiguous float4 along e.
// Block = 4 waves x 64 q-rows (m=4); 32 chunks of 64 keys; LDS = 24.6 KB.
// ---------------------------------------------------------------------------
__global__ __launch_bounds__(256, 2) void attn_mfma_kernel(
    const float* __restrict__ Qf, const ushort_t* __restrict__ Khi,
    const ushort_t* __restrict__ Klo, const ushort_t* __restrict__ Vt,
    float* __restrict__ out)
{
    __shared__ __align__(16) ushort_t Khs[64 * 64];
    __shared__ __align__(16) ushort_t Kls[64 * 64];
    __shared__ __align__(16) ushort_t Vts[64 * 64];

    const int qt  = blockIdx.x;       // 0..7 (256 q-rows per block)
    const int bn  = blockIdx.y;       // 0..63
    const int tid = threadIdx.x;
    const int w    = tid >> 6;
    const int lane = tid & 63;
    const int col  = lane & 15;
    const int quad = lane >> 4;

    const ushort_t* Kh_g = Khi + (size_t)bn * SEQ * HD;
    const ushort_t* Kl_g = Klo + (size_t)bn * SEQ * HD;
    const ushort_t* Vt_g = Vt  + (size_t)bn * HD * SEQ;

    // ---- Q fragments (B operand: n=lane&15=qrow, k=quad*8+j=e), scaled by
    //      log2e/sqrt(64), split hi/lo. Same loads as r7.
    union { bf16x8 v; short s[8]; } qh[4][2], ql[4][2];
    #pragma unroll
    for (int m = 0; m < 4; m++) {
        const int qrow = qt * 256 + w * 64 + m * 16 + col;
        const float* qp = Qf + ((size_t)bn * SEQ + qrow) * HD;
        #pragma unroll
        for (int ks = 0; ks < 2; ks++) {
            float qv[8];
            f32x4 a = *(const f32x4*)(qp + ks * 32 + quad * 8);
            f32x4 b = *(const f32x4*)(qp + ks * 32 + quad * 8 + 4);
            qv[0]=a[0]; qv[1]=a[1]; qv[2]=a[2]; qv[3]=a[3];
            qv[4]=b[0]; qv[5]=b[1]; qv[6]=b[2]; qv[7]=b[3];
            #pragma unroll
            for (int j = 0; j < 8; j++) {
                float xsc = qv[j] * (0.125f * 1.44269504088896f);   // log2e/sqrt(64)
                ushort_t hi = f2bf(xsc);
                ushort_t lo = f2bf(xsc - bf2f(hi));
                qh[m][ks].s[j] = (short)hi;
                ql[m][ks].s[j] = (short)lo;
            }
        }
    }

    f32x4 O[4][4] = {};                                   // O^T: [m][e-tile]
    float m_i[4] = {-1e30f, -1e30f, -1e30f, -1e30f};      // per-lane (qrow=col)
    float L[4]   = {0.f, 0.f, 0.f, 0.f};                  // per-lane partial denom

    for (int ch = 0; ch < 32; ch++) {
        __syncthreads();   // previous chunk fully consumed
        #pragma unroll
        for (int t = 0; t < 2; t++) {
            int G   = (w * 2 + t) * 64 + lane;            // granule 0..511
            int key = G >> 3;                              // key (K) / e (V)
            int blk = (G & 7) ^ (key & 7);                 // swizzled 8-elem block
            size_t koff = (size_t)(ch * 64 + key) * HD + blk * 8;
            size_t voff = (size_t)key * SEQ + ch * 64 + blk * 8;
            GLOAD_LDS16(Kh_g + koff, Khs + (w * 2 + t) * 512);
            GLOAD_LDS16(Kl_g + koff, Kls + (w * 2 + t) * 512);
            GLOAD_LDS16(Vt_g + voff, Vts + (w * 2 + t) * 512);
        }
        __syncthreads();   // staged data visible

        // ---- S^T = K Q^T (3-pass split): K frags read once, reused over m
        f32x4 St[4][4] = {};                              // [m][key-tile]
        #pragma unroll
        for (int ks = 0; ks < 2; ks++) {
            #pragma unroll
            for (int t = 0; t < 4; t++) {
                int key = t * 16 + col;
                int g = key * 8 + ((ks * 4 + quad) ^ (key & 7));
                bf16x8 kh = *(const bf16x8*)&Khs[g * 8];
                bf16x8 kl = *(const bf16x8*)&Kls[g * 8];
                #pragma unroll
                for (int m = 0; m < 4; m++) {
                    St[m][t] = MFMA16(kh, qh[m][ks].v, St[m][t]);
                    St[m][t] = MFMA16(kh, ql[m][ks].v, St[m][t]);
                    St[m][t] = MFMA16(kl, qh[m][ks].v, St[m][t]);
                }
            }
        }

        // ---- V^T A-fragments (m=lane&15=e, k=quad*4+j=key): b64 reads,
        //      shared across all m-tiles; issued before softmax for overlap
        bf16x4 vfrag[4][4];                               // [e-tile][key-tile]
        #pragma unroll
        for (int u = 0; u < 4; u++) {
            int rowbase = (u * 16 + col) * 64;
            #pragma unroll
            for (int t = 0; t < 4; t++) {
                int g = (t * 2 + (quad >> 1)) ^ (col & 7);
                vfrag[u][t] = *(const bf16x4*)&Vts[rowbase + g * 8 + (quad & 1) * 4];
            }
        }

        // ---- per-m: softmax (scalar state) + PV from registers
        #pragma unroll
        for (int m = 0; m < 4; m++) {
            float mx = St[m][0][0];
            #pragma unroll
            for (int t = 0; t < 4; t++)
                #pragma unroll
                for (int r = 0; r < 4; r++) mx = fmaxf(mx, St[m][t][r]);
            mx = fmaxf(mx, __shfl_xor(mx, 16));
            mx = fmaxf(mx, __shfl_xor(mx, 32));
            float mnew = fmaxf(m_i[m], mx);
            float al   = fast_exp2(m_i[m] - mnew);
            m_i[m] = mnew;

            float psum = 0.f;
            bf16x4 pf[4];                                 // P^T B-frags per key-tile
            #pragma unroll
            for (int t = 0; t < 4; t++) {
                #pragma unroll
                for (int r = 0; r < 4; r++) {
                    float p = fast_exp2(St[m][t][r] - mnew);
                    psum += p;
                    pf[t][r] = (short)f2bf(p);
                }
            }
            L[m] = L[m] * al + psum;                      // per-lane partial; al row-uniform
            #pragma unroll
            for (int u = 0; u < 4; u++) {
                O[m][u][0] *= al; O[m][u][1] *= al;
                O[m][u][2] *= al; O[m][u][3] *= al;
            }
            #pragma unroll
            for (int t = 0; t < 4; t++)
                #pragma unroll
                for (int u = 0; u < 4; u++)
                    O[m][u] = MFMA_PV(vfrag[u][t], pf[t], O[m][u]);
        }
    }

    // ---- epilogue: finish L across quads (2 shuffles), write float4 along e
    const int b = bn >> 4, n = bn & 15;
    #pragma unroll
    for (int m = 0; m < 4; m++) {
        float Lr = L[m];
        Lr += __shfl_xor(Lr, 16);
        Lr += __shfl_xor(Lr, 32);
        float inv = 1.0f / Lr;
        int l = qt * 256 + w * 64 + m * 16 + col;
        size_t base = ((size_t)(b * SEQ + l)) * (NHEADS * HD) + n * HD;
        #pragma unroll
        for (int u = 0; u < 4; u++) {
            f32x4 o;
            o[0] = O[m][u][0] * inv; o[1] = O[m][u][1] * inv;
            o[2] = O[m][u][2] * inv; o[3] = O[m][u][3] * inv;
            *(f32x4*)&out[base + u * 16 + quad * 4] = o;
        }
    }
}

// ---------------------------------------------------------------------------
extern "C" void kernel_launch(void* const* d_in, const int* in_sizes, int n_in,
                              void* d_out, int out_size, void* d_ws, size_t ws_size,
                              hipStream_t stream) {
    const float* x  = (const float*)d_in[0];
    const float* wk = (const float*)d_in[1];
    const float* wq = (const float*)d_in[2];
    const float* wv = (const float*)d_in[3];
    float* out = (float*)d_out;

    // ws layout (111 MB): Xh | Xl (aliased by Vt after proj_qk) | Bqh | Bql | Bvh | Qf | Khi | Klo
    ushort_t* Xh  = (ushort_t*)d_ws;
    ushort_t* Xl  = Xh + NM;
    ushort_t* Vt  = Xl;                      // alias: Xl dead once proj_qk finishes
    ushort_t* Bqh = Xl + NM;                 // [2048][1024]
    ushort_t* Bql = Bqh + 2097152;
    ushort_t* Bvh = Bql + 2097152;           // [1024][1024]
    float*    Qf  = (float*)(Bvh + 1048576);
    ushort_t* Khi = (ushort_t*)(Qf + NM);
    ushort_t* Klo = Khi + NM;

    convert_x<<<2048, 256, 0, stream>>>(x, Xh, Xl);
    convert_w<<<768, 256, 0, stream>>>(wk, wq, wv, Bqh, Bql, Bvh);
    proj_qk<<<dim3(64, 16), 256, 0, stream>>>(Xh, Xl, Bqh, Bql, Qf, Khi, Klo);
    proj_v<<<dim3(8, 64), 256, 0, stream>>>(Bvh, Xh, Vt);
    attn_mfma_kernel<<<dim3(8, 64), 256, 0, stream>>>(Qf, Khi, Klo, Vt, out);
}

// Round 9
// 377.855 us; speedup vs baseline: 2.3011x; 1.0144x over previous
//
#include <hip/hip_runtime.h>
#include <math.h>

#define DIMX   1024
#define NHEADS 16
#define HD     64
#define BATCH  4
#define SEQ    2048
#define NM     (BATCH * NHEADS * SEQ * HD)   // 8388608 elems per Q/K/V tensor

typedef unsigned short ushort_t;
typedef __attribute__((ext_vector_type(8))) short bf16x8;
typedef __attribute__((ext_vector_type(4))) short bf16x4;
typedef __attribute__((ext_vector_type(4))) float f32x4;

#define MFMA16(a, b, c) __builtin_amdgcn_mfma_f32_16x16x32_bf16(a, b, c, 0, 0, 0)

// K=16 bf16 MFMA (A,B = 4 bf16 each). gfx90a+ "_1k" builtin; asm fallback.
#if __has_builtin(__builtin_amdgcn_mfma_f32_16x16x16bf16_1k)
#define MFMA_PV(a, b, c) __builtin_amdgcn_mfma_f32_16x16x16bf16_1k(a, b, c, 0, 0, 0)
#else
static __device__ __forceinline__ f32x4 mfma_pv_asm(bf16x4 a, bf16x4 b, f32x4 c) {
    asm("v_mfma_f32_16x16x16_bf16 %0, %1, %2, %0" : "+v"(c) : "v"(a), "v"(b));
    return c;
}
#define MFMA_PV(a, b, c) mfma_pv_asm(a, b, c)
#endif

// round-to-nearest-even fp32 -> bf16 bits
__device__ __forceinline__ ushort_t f2bf(float x) {
    unsigned u = __float_as_uint(x);
    u += 0x7fffu + ((u >> 16) & 1u);
    return (ushort_t)(u >> 16);
}
__device__ __forceinline__ float bf2f(ushort_t h) {
    return __uint_as_float(((unsigned)h) << 16);
}

// pack two fp32 -> two TRUNCATED bf16 in one dword (lo in low half).
// v_perm_b32: sel bytes 0-3 pick from src1 (=b), 4-7 from src0 (=a).
__device__ __forceinline__ unsigned pack_bf16_trunc(float lo, float hi) {
#if __has_builtin(__builtin_amdgcn_perm)
    return __builtin_amdgcn_perm(__float_as_uint(hi), __float_as_uint(lo), 0x07060302u);
#else
    return (__float_as_uint(lo) >> 16) | (__float_as_uint(hi) & 0xFFFF0000u);
#endif
}
__device__ __forceinline__ float trunc_bf(float x) {
    return __uint_as_float(__float_as_uint(x) & 0xFFFF0000u);
}

// raw v_exp_f32 (no ocml edge-case wrapper) — guarded
__device__ __forceinline__ float fast_exp2(float x) {
#if __has_builtin(__builtin_amdgcn_exp2f)
    return __builtin_amdgcn_exp2f(x);
#else
    return exp2f(x);
#endif
}

// async global->LDS, 16B per lane; LDS base wave-uniform (HW adds lane*16)
#define GLOAD_LDS16(g, l) \
    __builtin_amdgcn_global_load_lds((const __attribute__((address_space(1))) unsigned int*)(g), \
                                     (__attribute__((address_space(3))) unsigned int*)(l), 16, 0, 0)

// ---------------------------------------------------------------------------
// convert_x: split x fp32 -> Xhi, Xlo bf16.  (unchanged)
// ---------------------------------------------------------------------------
__global__ __launch_bounds__(256) void convert_x(
    const float* __restrict__ x, ushort_t* __restrict__ Xh, ushort_t* __restrict__ Xl)
{
    int i = blockIdx.x * 256 + threadIdx.x;
    #pragma unroll
    for (int t = 0; t < 4; t++) {
        int idx = t * 524288 + i;
        f32x4 v = ((const f32x4*)x)[idx];
        ushort4 hi, lo;
        hi.x = f2bf(v[0]); lo.x = f2bf(v[0] - bf2f(hi.x));
        hi.y = f2bf(v[1]); lo.y = f2bf(v[1] - bf2f(hi.y));
        hi.z = f2bf(v[2]); lo.z = f2bf(v[2] - bf2f(hi.z));
        hi.w = f2bf(v[3]); lo.w = f2bf(v[3] - bf2f(hi.w));
        ((ushort4*)Xh)[idx] = hi;
        ((ushort4*)Xl)[idx] = lo;
    }
}

// ---------------------------------------------------------------------------
// convert_w: transpose w[n][d][e] -> Wt[e'][d], split hi/lo bf16. (unchanged)
// ---------------------------------------------------------------------------
__global__ __launch_bounds__(256) void convert_w(
    const float* __restrict__ wk, const float* __restrict__ wq, const float* __restrict__ wv,
    ushort_t* __restrict__ Bqh, ushort_t* __restrict__ Bql, ushort_t* __restrict__ Bvh)
{
    __shared__ float Ts[64][65];
    const int bid = blockIdx.x;
    const int mat = bid >> 8;
    const int rem = bid & 255;
    const int n  = rem >> 4;
    const int dt = rem & 15;
    const float* w = (mat == 0) ? wq : (mat == 1) ? wk : wv;
    const int tid = threadIdx.x;

    #pragma unroll
    for (int t = 0; t < 16; t++) {
        int i = tid + t * 256;
        int r = i >> 6, e = i & 63;
        Ts[r][e] = w[((size_t)n * 1024 + dt * 64 + r) * 64 + e];
    }
    __syncthreads();
    #pragma unroll
    for (int t = 0; t < 16; t++) {
        int i = tid + t * 256;
        int e = i >> 6, r = i & 63;
        float v = Ts[r][e];
        ushort_t hi = f2bf(v);
        size_t o = (size_t)(n * 64 + e) * 1024 + dt * 64 + r;
        if (mat < 2) {
            Bqh[(size_t)mat * 1048576 + o] = hi;
            Bql[(size_t)mat * 1048576 + o] = f2bf(v - bf2f(hi));
        } else {
            Bvh[o] = hi;
        }
    }
}

// ---------------------------------------------------------------------------
// proj_qk: 3-pass split-bf16 MFMA GEMM. (unchanged)
// ---------------------------------------------------------------------------
__global__ __launch_bounds__(256) void proj_qk(
    const ushort_t* __restrict__ Xh, const ushort_t* __restrict__ Xl,
    const ushort_t* __restrict__ Bh, const ushort_t* __restrict__ Bl,
    float* __restrict__ Qf, ushort_t* __restrict__ Khi, ushort_t* __restrict__ Klo)
{
    __shared__ __align__(16) ushort_t Ah[128 * 64];
    __shared__ __align__(16) ushort_t Al[128 * 64];
    __shared__ __align__(16) ushort_t Bhs[128 * 64];
    __shared__ __align__(16) ushort_t Bls[128 * 64];

    const int mt = blockIdx.x, nt = blockIdx.y;
    const int tid = threadIdx.x;
    const int w = tid >> 6, lane = tid & 63, col = lane & 15, quad = lane >> 4;
    const int wm = w & 1, wn = w >> 1;

    f32x4 acc[4][4] = {};

    for (int kc = 0; kc < 1024; kc += 64) {
        __syncthreads();
        #pragma unroll
        for (int i = 0; i < 4; i++) {
            int s = (w * 4 + i) * 64 + lane;
            int r = s >> 3, j = s & 7, g = j ^ (r & 7);
            size_t aoff = (size_t)(mt * 128 + r) * 1024 + kc + g * 8;
            size_t boff = (size_t)(nt * 128 + r) * 1024 + kc + g * 8;
            GLOAD_LDS16(Xh + aoff, Ah  + (size_t)(w * 4 + i) * 512);
            GLOAD_LDS16(Xl + aoff, Al  + (size_t)(w * 4 + i) * 512);
            GLOAD_LDS16(Bh + boff, Bhs + (size_t)(w * 4 + i) * 512);
            GLOAD_LDS16(Bl + boff, Bls + (size_t)(w * 4 + i) * 512);
        }
        __syncthreads();
        #pragma unroll
        for (int kk = 0; kk < 2; kk++) {
            bf16x8 a_h[4], a_l[4], b_h[4], b_l[4];
            const int gi = kk * 4 + quad;
            #pragma unroll
            for (int t = 0; t < 4; t++) {
                int rA = wm * 64 + t * 16 + col;
                int jA = gi ^ (rA & 7);
                a_h[t] = *(const bf16x8*)&Ah[(rA * 8 + jA) * 8];
                a_l[t] = *(const bf16x8*)&Al[(rA * 8 + jA) * 8];
                int rB = wn * 64 + t * 16 + col;
                int jB = gi ^ (rB & 7);
                b_h[t] = *(const bf16x8*)&Bhs[(rB * 8 + jB) * 8];
                b_l[t] = *(const bf16x8*)&Bls[(rB * 8 + jB) * 8];
            }
            #pragma unroll
            for (int t = 0; t < 4; t++)
                #pragma unroll
                for (int u = 0; u < 4; u++) {
                    acc[t][u] = MFMA16(a_h[t], b_h[u], acc[t][u]);
                    acc[t][u] = MFMA16(a_l[t], b_h[u], acc[t][u]);
                    acc[t][u] = MFMA16(a_h[t], b_l[u], acc[t][u]);
                }
        }
    }

    const bool isQ = (nt < 8);
    #pragma unroll
    for (int t = 0; t < 4; t++) {
        #pragma unroll
        for (int u = 0; u < 4; u++) {
            int np = nt * 128 + wn * 64 + u * 16 + col;
            int head = (np >> 6) & 15, e = np & 63;
            #pragma unroll
            for (int rr = 0; rr < 4; rr++) {
                int mm = mt * 128 + wm * 64 + t * 16 + quad * 4 + rr;
                int bi = mm >> 11, l = mm & 2047;
                size_t base = (((size_t)bi * NHEADS + head) * SEQ + l) * HD + e;
                float v = acc[t][u][rr];
                if (isQ) {
                    Qf[base] = v;
                } else {
                    ushort_t hi = f2bf(v);
                    Khi[base] = hi;
                    Klo[base] = f2bf(v - bf2f(hi));
                }
            }
        }
    }
}

// ---------------------------------------------------------------------------
// proj_v: 1-pass bf16, operand-swapped for transposed-V output. (unchanged)
// ---------------------------------------------------------------------------
__global__ __launch_bounds__(256) void proj_v(
    const ushort_t* __restrict__ Wvh, const ushort_t* __restrict__ Xh,
    ushort_t* __restrict__ Vt)
{
    __shared__ __align__(16) ushort_t Ah[128 * 64];
    __shared__ __align__(16) ushort_t Bhs[128 * 64];

    const int mt = blockIdx.x, nt = blockIdx.y;
    const int tid = threadIdx.x;
    const int w = tid >> 6, lane = tid & 63, col = lane & 15, quad = lane >> 4;
    const int wm = w & 1, wn = w >> 1;

    f32x4 acc[4][4] = {};

    for (int kc = 0; kc < 1024; kc += 64) {
        __syncthreads();
        #pragma unroll
        for (int i = 0; i < 4; i++) {
            int s = (w * 4 + i) * 64 + lane;
            int r = s >> 3, j = s & 7, g = j ^ (r & 7);
            size_t aoff = (size_t)(mt * 128 + r) * 1024 + kc + g * 8;
            size_t boff = (size_t)(nt * 128 + r) * 1024 + kc + g * 8;
            GLOAD_LDS16(Wvh + aoff, Ah  + (size_t)(w * 4 + i) * 512);
            GLOAD_LDS16(Xh  + boff, Bhs + (size_t)(w * 4 + i) * 512);
        }
        __syncthreads();
        #pragma unroll
        for (int kk = 0; kk < 2; kk++) {
            bf16x8 a_h[4], b_h[4];
            const int gi = kk * 4 + quad;
            #pragma unroll
            for (int t = 0; t < 4; t++) {
                int rA = wm * 64 + t * 16 + col;
                a_h[t] = *(const bf16x8*)&Ah[(rA * 8 + (gi ^ (rA & 7))) * 8];
                int rB = wn * 64 + t * 16 + col;
                b_h[t] = *(const bf16x8*)&Bhs[(rB * 8 + (gi ^ (rB & 7))) * 8];
            }
            #pragma unroll
            for (int t = 0; t < 4; t++)
                #pragma unroll
                for (int u = 0; u < 4; u++)
                    acc[t][u] = MFMA16(a_h[t], b_h[u], acc[t][u]);
        }
    }

    #pragma unroll
    for (int t = 0; t < 4; t++) {
        #pragma unroll
        for (int rr = 0; rr < 4; rr++) {
            int ep = mt * 128 + wm * 64 + t * 16 + quad * 4 + rr;
            int head = ep >> 6, e = ep & 63;
            #pragma unroll
            for (int u = 0; u < 4; u++) {
                int lg = nt * 128 + wn * 64 + u * 16 + col;
                int bi = lg >> 11, l = lg & 2047;
                Vt[(((size_t)bi * NHEADS + head) * HD + e) * SEQ + l] = f2bf(acc[t][u][rr]);
            }
        }
    }
}

// ---------------------------------------------------------------------------
// Flash attention, operand-swapped (r8 structure) + round-9 changes:
//   m=2 (32 q-rows/wave) -> grid 1024 blocks = 4 blocks/CU = 4 waves/SIMD
//   for cross-wave overlap of the serial QK->softmax->PV chunk chain.
//   P packed via v_perm truncation; psum sums the SAME truncated values so
//   L is exactly consistent with the P fed to the PV MFMA.
// ---------------------------------------------------------------------------
__global__ __launch_bounds__(256, 4) void attn_mfma_kernel(
    const float* __restrict__ Qf, const ushort_t* __restrict__ Khi,
    const ushort_t* __restrict__ Klo, const ushort_t* __restrict__ Vt,
    float* __restrict__ out)
{
    __shared__ __align__(16) ushort_t Khs[64 * 64];
    __shared__ __align__(16) ushort_t Kls[64 * 64];
    __shared__ __align__(16) ushort_t Vts[64 * 64];

    const int qt  = blockIdx.x;       // 0..15 (128 q-rows per block)
    const int bn  = blockIdx.y;       // 0..63
    const int tid = threadIdx.x;
    const int w    = tid >> 6;
    const int lane = tid & 63;
    const int col  = lane & 15;
    const int quad = lane >> 4;

    const ushort_t* Kh_g = Khi + (size_t)bn * SEQ * HD;
    const ushort_t* Kl_g = Klo + (size_t)bn * SEQ * HD;
    const ushort_t* Vt_g = Vt  + (size_t)bn * HD * SEQ;

    // ---- Q fragments (B operand: n=lane&15=qrow, k=quad*8+j=e), scaled by
    //      log2e/sqrt(64), split hi/lo.
    union { bf16x8 v; short s[8]; } qh[2][2], ql[2][2];
    #pragma unroll
    for (int m = 0; m < 2; m++) {
        const int qrow = qt * 128 + w * 32 + m * 16 + col;
        const float* qp = Qf + ((size_t)bn * SEQ + qrow) * HD;
        #pragma unroll
        for (int ks = 0; ks < 2; ks++) {
            float qv[8];
            f32x4 a = *(const f32x4*)(qp + ks * 32 + quad * 8);
            f32x4 b = *(const f32x4*)(qp + ks * 32 + quad * 8 + 4);
            qv[0]=a[0]; qv[1]=a[1]; qv[2]=a[2]; qv[3]=a[3];
            qv[4]=b[0]; qv[5]=b[1]; qv[6]=b[2]; qv[7]=b[3];
            #pragma unroll
            for (int j = 0; j < 8; j++) {
                float xsc = qv[j] * (0.125f * 1.44269504088896f);   // log2e/sqrt(64)
                ushort_t hi = f2bf(xsc);
                ushort_t lo = f2bf(xsc - bf2f(hi));
                qh[m][ks].s[j] = (short)hi;
                ql[m][ks].s[j] = (short)lo;
            }
        }
    }

    f32x4 O[2][4] = {};                                   // O^T: [m][e-tile]
    float m_i[2] = {-1e30f, -1e30f};                      // per-lane (qrow=col)
    float L[2]   = {0.f, 0.f};                            // per-lane partial denom

    for (int ch = 0; ch < 32; ch++) {
        __syncthreads();   // previous chunk fully consumed
        #pragma unroll
        for (int t = 0; t < 2; t++) {
            int G   = (w * 2 + t) * 64 + lane;            // granule 0..511
            int key = G >> 3;                              // key (K) / e (V)
            int blk = (G & 7) ^ (key & 7);                 // swizzled 8-elem block
            size_t koff = (size_t)(ch * 64 + key) * HD + blk * 8;
            size_t voff = (size_t)key * SEQ + ch * 64 + blk * 8;
            GLOAD_LDS16(Kh_g + koff, Khs + (w * 2 + t) * 512);
            GLOAD_LDS16(Kl_g + koff, Kls + (w * 2 + t) * 512);
            GLOAD_LDS16(Vt_g + voff, Vts + (w * 2 + t) * 512);
        }
        __syncthreads();   // staged data visible

        // ---- S^T = K Q^T (3-pass split): K frags read once, reused over m
        f32x4 St[2][4] = {};                              // [m][key-tile]
        #pragma unroll
        for (int ks = 0; ks < 2; ks++) {
            #pragma unroll
            for (int t = 0; t < 4; t++) {
                int key = t * 16 + col;
                int g = key * 8 + ((ks * 4 + quad) ^ (key & 7));
                bf16x8 kh = *(const bf16x8*)&Khs[g * 8];
                bf16x8 kl = *(const bf16x8*)&Kls[g * 8];
                #pragma unroll
                for (int m = 0; m < 2; m++) {
                    St[m][t] = MFMA16(kh, qh[m][ks].v, St[m][t]);
                    St[m][t] = MFMA16(kh, ql[m][ks].v, St[m][t]);
                    St[m][t] = MFMA16(kl, qh[m][ks].v, St[m][t]);
                }
            }
        }

        // ---- V^T A-fragments (m=lane&15=e, k=quad*4+j=key): b64 reads
        bf16x4 vfrag[4][4];                               // [e-tile][key-tile]
        #pragma unroll
        for (int u = 0; u < 4; u++) {
            int rowbase = (u * 16 + col) * 64;
            #pragma unroll
            for (int t = 0; t < 4; t++) {
                int g = (t * 2 + (quad >> 1)) ^ (col & 7);
                vfrag[u][t] = *(const bf16x4*)&Vts[rowbase + g * 8 + (quad & 1) * 4];
            }
        }

        // ---- per-m: softmax (scalar per-lane state) + PV from registers
        #pragma unroll
        for (int m = 0; m < 2; m++) {
            float mx = St[m][0][0];
            #pragma unroll
            for (int t = 0; t < 4; t++)
                #pragma unroll
                for (int r = 0; r < 4; r++) mx = fmaxf(mx, St[m][t][r]);
            mx = fmaxf(mx, __shfl_xor(mx, 16));
            mx = fmaxf(mx, __shfl_xor(mx, 32));
            float mnew = fmaxf(m_i[m], mx);
            float al   = fast_exp2(m_i[m] - mnew);
            m_i[m] = mnew;

            float psum = 0.f;
            bf16x4 pf[4];                                 // P^T B-frags per key-tile
            #pragma unroll
            for (int t = 0; t < 4; t++) {
                float p0 = fast_exp2(St[m][t][0] - mnew);
                float p1 = fast_exp2(St[m][t][1] - mnew);
                float p2 = fast_exp2(St[m][t][2] - mnew);
                float p3 = fast_exp2(St[m][t][3] - mnew);
                // truncated-bf16 P; psum over the SAME truncated values
                psum += trunc_bf(p0) + trunc_bf(p1) + trunc_bf(p2) + trunc_bf(p3);
                union { unsigned u[2]; bf16x4 v; } pk;
                pk.u[0] = pack_bf16_trunc(p0, p1);
                pk.u[1] = pack_bf16_trunc(p2, p3);
                pf[t] = pk.v;
            }
            L[m] = L[m] * al + psum;                      // per-lane partial; al row-uniform
            #pragma unroll
            for (int u = 0; u < 4; u++) {
                O[m][u][0] *= al; O[m][u][1] *= al;
                O[m][u][2] *= al; O[m][u][3] *= al;
            }
            #pragma unroll
            for (int t = 0; t < 4; t++)
                #pragma unroll
                for (int u = 0; u < 4; u++)
                    O[m][u] = MFMA_PV(vfrag[u][t], pf[t], O[m][u]);
        }
    }

    // ---- epilogue: finish L across quads (2 shuffles), write float4 along e
    const int b = bn >> 4, n = bn & 15;
    #pragma unroll
    for (int m = 0; m < 2; m++) {
        float Lr = L[m];
        Lr += __shfl_xor(Lr, 16);
        Lr += __shfl_xor(Lr, 32);
        float inv = 1.0f / Lr;
        int l = qt * 128 + w * 32 + m * 16 + col;
        size_t base = ((size_t)(b * SEQ + l)) * (NHEADS * HD) + n * HD;
        #pragma unroll
        for (int u = 0; u < 4; u++) {
            f32x4 o;
            o[0] = O[m][u][0] * inv; o[1] = O[m][u][1] * inv;
            o[2] = O[m][u][2] * inv; o[3] = O[m][u][3] * inv;
            *(f32x4*)&out[base + u * 16 + quad * 4] = o;
        }
    }
}

// ---------------------------------------------------------------------------
extern "C" void kernel_launch(void* const* d_in, const int* in_sizes, int n_in,
                              void* d_out, int out_size, void* d_ws, size_t ws_size,
                              hipStream_t stream) {
    const float* x  = (const float*)d_in[0];
    const float* wk = (const float*)d_in[1];
    const float* wq = (const float*)d_in[2];
    const float* wv = (const float*)d_in[3];
    float* out = (float*)d_out;

    // ws layout (111 MB): Xh | Xl (aliased by Vt after proj_qk) | Bqh | Bql | Bvh | Qf | Khi | Klo
    ushort_t* Xh  = (ushort_t*)d_ws;
    ushort_t* Xl  = Xh + NM;
    ushort_t* Vt  = Xl;                      // alias: Xl dead once proj_qk finishes
    ushort_t* Bqh = Xl + NM;                 // [2048][1024]
    ushort_t* Bql = Bqh + 2097152;
    ushort_t* Bvh = Bql + 2097152;           // [1024][1024]
    float*    Qf  = (float*)(Bvh + 1048576);
    ushort_t* Khi = (ushort_t*)(Qf + NM);
    ushort_t* Klo = Khi + NM;

    convert_x<<<2048, 256, 0, stream>>>(x, Xh, Xl);
    convert_w<<<768, 256, 0, stream>>>(wk, wq, wv, Bqh, Bql, Bvh);
    proj_qk<<<dim3(64, 16), 256, 0, stream>>>(Xh, Xl, Bqh, Bql, Qf, Khi, Klo);
    proj_v<<<dim3(8, 64), 256, 0, stream>>>(Bvh, Xh, Vt);
    attn_mfma_kernel<<<dim3(16, 64), 256, 0, stream>>>(Qf, Khi, Klo, Vt, out);
}